// Round 6
// baseline (430.006 us; speedup 1.0000x reference)
//
#include <hip/hip_runtime.h>
#include <hip/hip_bf16.h>

#define BB 16
#define CC 2048
#define HWW 1024
#define DD 256
#define BN_RSQRT 0.9999950000374997f

typedef short bf16x8 __attribute__((ext_vector_type(8)));
typedef float f32x4 __attribute__((ext_vector_type(4)));
typedef unsigned short u16x8 __attribute__((ext_vector_type(8)));
typedef unsigned short u16x4 __attribute__((ext_vector_type(4)));
typedef unsigned short u16;

typedef __attribute__((address_space(1))) const unsigned GU;
typedef __attribute__((address_space(3))) unsigned LU;
__device__ __forceinline__ void gload16(const void* g, void* l) {
    __builtin_amdgcn_global_load_lds((GU*)g, (LU*)l, 16, 0, 0);
}

// ---- bf16 split helpers (RNE) ----
__device__ __forceinline__ unsigned short f2bf(float x) {
    unsigned u = __builtin_bit_cast(unsigned, x);
    unsigned r = u + 0x7FFFu + ((u >> 16) & 1u);
    return (unsigned short)(r >> 16);
}
__device__ __forceinline__ float bf2f(unsigned short h) {
    unsigned u = ((unsigned)h) << 16;
    return __builtin_bit_cast(float, u);
}
__device__ __forceinline__ void split2(float x, unsigned short& hi, unsigned short& lo) {
    hi = f2bf(x);
    lo = f2bf(x - bf2f(hi));
}
__device__ __forceinline__ void split16(const float* v, u16x8& h0, u16x8& h1,
                                        u16x8& l0, u16x8& l1) {
    #pragma unroll
    for (int j = 0; j < 8; ++j) { unsigned short hh, ll; split2(v[j], hh, ll); h0[j] = hh; l0[j] = ll; }
    #pragma unroll
    for (int j = 0; j < 8; ++j) { unsigned short hh, ll; split2(v[8 + j], hh, ll); h1[j] = hh; l1[j] = ll; }
}

struct BSet { float4 f0, f1, f2, f3; u16x8 h0, h1, l0, l1; };
struct RegsA { float4 f[4]; u16x8 h[2]; u16x8 l[2]; };
struct RegsB { float4 f[4]; u16x8 h[2]; u16x8 l[2]; };

// ---------------------------------------------------------------------------
// split fp32 -> hi/lo bf16 planes (weights only)
// ---------------------------------------------------------------------------
__global__ __launch_bounds__(256) void split_k(const float* __restrict__ in,
                                               u16* __restrict__ hi, u16* __restrict__ lo,
                                               long long n8) {
    long long i = (long long)blockIdx.x * 256 + threadIdx.x;
    if (i >= n8) return;
    const float4* p = (const float4*)in + i * 2;
    float4 a = p[0], b = p[1];
    float xs[8] = {a.x, a.y, a.z, a.w, b.x, b.y, b.z, b.w};
    u16x8 h, l;
    #pragma unroll
    for (int j = 0; j < 8; ++j) { unsigned short hh, ll; split2(xs[j], hh, ll); h[j] = hh; l[j] = ll; }
    *(u16x8*)(hi + i * 8) = h;
    *(u16x8*)(lo + i * 8) = l;
}

// ---------------------------------------------------------------------------
// Deep-pipelined 8-phase split-bf16 MFMA GEMM (NT): C[M,N]=sum_k A[m][k]B[n][k]
// 256x256 tile, BK=32, 8 waves, dbuf LDS 2x64KB.
// A: bf16 hi/lo planes in GLOBAL, staged via global_load_lds (1 tile ahead,
//    linear LDS + inverse-swizzled source). B: reg-staged 2 tiles ahead
//    (2 named sets), counted vmcnt (8/4, never 0 mid-loop), split on the fly.
// BFMT: 0 = fp32 rows [n][k];  1 = bf16 planes;  3 = v2l k'-remap (G3):
//       B'[h][k'] = v2l[(k'>>10)*1024 + h][k'&1023]
// EPI : 0 = fp32 store;  1 = relu(g*BN_RSQRT*x + b)
// FUSE2: grid.z=32, op = z>>4.   KS: K-split, grid.z = 16*KS, part kz = z%KS.
// ---------------------------------------------------------------------------
template <int BFMT, int EPI, int FUSE2, int KS>
__global__ __launch_bounds__(512, 2) void gemm8(
    const u16* __restrict__ Ah0, const u16* __restrict__ Al0,
    const u16* __restrict__ Ah1, const u16* __restrict__ Al1,
    long long aB, int lda,
    const void* __restrict__ B0a, const void* __restrict__ B0b,
    const void* __restrict__ B1a, const void* __restrict__ B1b,
    long long bB, int ldb,
    float* __restrict__ C0, float* __restrict__ C1,
    long long cB, long long kB, int ldc,
    int K,
    const float* __restrict__ g0, const float* __restrict__ bb0,
    const float* __restrict__ g1, const float* __restrict__ bb1)
{
    __shared__ __attribute__((aligned(16))) char smem[2][65536];

    // bijective XCD-chunk swizzle (nwg % 8 == 0 for all grids used)
    const int gx = gridDim.x, gy = gridDim.y;
    int nwg = gx * gy * gridDim.z;
    int id = blockIdx.x + gx * (blockIdx.y + gy * blockIdx.z);
    int chunk = nwg >> 3;
    int nid = (id & 7) * chunk + (id >> 3);
    int bx = nid % gx;
    int tmp = nid / gx;
    int by = tmp % gy;
    int bz = tmp / gy;

    const int t = threadIdx.x;
    const int n0 = bx * 256, m0 = by * 256;

    int op = 0, batch, kz = 0;
    if constexpr (FUSE2) { op = bz >> 4; batch = bz & 15; }
    else if constexpr (KS > 1) { batch = bz / KS; kz = bz - batch * KS; }
    else { batch = bz; }
    const int koff = kz * K;

    const u16* Ahp = (op ? Ah1 : Ah0) + (long long)batch * aB + koff;
    const u16* Alp = (op ? Al1 : Al0) + (long long)batch * aB + koff;
    const float* Bf = nullptr;
    const u16* Bh = nullptr;
    const u16* Bl = nullptr;
    if constexpr (BFMT == 1) {
        Bh = (const u16*)(op ? B1a : B0a) + (long long)batch * bB + koff;
        Bl = (const u16*)(op ? B1b : B0b) + (long long)batch * bB + koff;
    } else if constexpr (BFMT == 0) {
        Bf = (const float*)(op ? B1a : B0a) + (long long)batch * bB + koff;
    } else {
        Bf = (const float*)B0a + (long long)batch * bB;   // koff applied in loadB
    }
    float* Cb = ((EPI == 1 && FUSE2) ? (op ? C1 : C0) : C0)
              + (long long)batch * cB + (long long)kz * kB;
    const float* gp = op ? g1 : g0;
    const float* bp = op ? bb1 : bb0;

    // ---- staging coords ----
    // A gload: thread t -> chunks c = t and t+512 of each 16KB plane
    const int grow0 = t >> 2;                       // rows 0..127 (then +128)
    const int gs0 = ((t & 3) ^ ((grow0 >> 1) & 3)) * 8;  // inverse-swz source (u16)
    // B reg-stage: row ar, k-half ag, XOR'd dest slots
    const int ar = t >> 1, ag = t & 1;
    const int af = (ar >> 1) & 3;
    const int as0 = ((2 * ag) ^ af) * 16, as1 = ((2 * ag + 1) ^ af) * 16;

    // ---- fragment coords ----
    const int l = t & 63, w = t >> 6;
    const int wr = w >> 2, wc = w & 3;
    const int rl = l & 15, kq = l >> 4;
    const int sw16 = (kq ^ ((rl >> 1) & 3)) * 16;

    f32x4 acc[8][4];
    #pragma unroll
    for (int i = 0; i < 8; ++i)
        #pragma unroll
        for (int j = 0; j < 4; ++j)
            acc[i][j] = (f32x4){0.f, 0.f, 0.f, 0.f};

    auto gloadA = [&](int k0, char* sn) {
        const u16* ph = Ahp + (long long)(m0 + grow0) * lda + k0 + gs0;
        gload16(ph,                           sn + t * 16);
        gload16(ph + (long long)128 * lda,    sn + 8192 + t * 16);
        const u16* pl = Alp + (long long)(m0 + grow0) * lda + k0 + gs0;
        gload16(pl,                           sn + 16384 + t * 16);
        gload16(pl + (long long)128 * lda,    sn + 24576 + t * 16);
    };
    auto loadB = [&](int k0, BSet& s) {
        if constexpr (BFMT == 0) {
            const float* p = Bf + (long long)(n0 + ar) * ldb + k0 + ag * 16;
            s.f0 = *(const float4*)(p);
            s.f1 = *(const float4*)(p + 4);
            s.f2 = *(const float4*)(p + 8);
            s.f3 = *(const float4*)(p + 12);
        } else if constexpr (BFMT == 1) {
            const u16* ph = Bh + (long long)(n0 + ar) * ldb + k0 + ag * 16;
            s.h0 = *(const u16x8*)(ph);
            s.h1 = *(const u16x8*)(ph + 8);
            const u16* pl = Bl + (long long)(n0 + ar) * ldb + k0 + ag * 16;
            s.l0 = *(const u16x8*)(pl);
            s.l1 = *(const u16x8*)(pl + 8);
        } else {
            int col = koff + k0 + ag * 16;
            const float* p = Bf + ((long long)((col >> 10) << 10) + n0 + ar) * ldb
                           + (col & 1023);
            s.f0 = *(const float4*)(p);
            s.f1 = *(const float4*)(p + 4);
            s.f2 = *(const float4*)(p + 8);
            s.f3 = *(const float4*)(p + 12);
        }
    };
    auto writeB = [&](char* sn, BSet& s) {
        char* base = sn + 32768 + ar * 64;
        if constexpr (BFMT == 1) {
            *(u16x8*)(base + as0) = s.h0;
            *(u16x8*)(base + as1) = s.h1;
            *(u16x8*)(base + 16384 + as0) = s.l0;
            *(u16x8*)(base + 16384 + as1) = s.l1;
        } else {
            float v[16] = {s.f0.x, s.f0.y, s.f0.z, s.f0.w,
                           s.f1.x, s.f1.y, s.f1.z, s.f1.w,
                           s.f2.x, s.f2.y, s.f2.z, s.f2.w,
                           s.f3.x, s.f3.y, s.f3.z, s.f3.w};
            u16x8 h0, h1, l0, l1;
            split16(v, h0, h1, l0, l1);
            *(u16x8*)(base + as0) = h0;
            *(u16x8*)(base + as1) = h1;
            *(u16x8*)(base + 16384 + as0) = l0;
            *(u16x8*)(base + 16384 + as1) = l1;
        }
    };

#define PHASE(MH, NH, EXTRA) do {                                              \
    bf16x8 fah[4], fal[4], fbh[2], fbl[2];                                     \
    _Pragma("unroll")                                                          \
    for (int i2 = 0; i2 < 4; ++i2) {                                           \
        int off = (wr * 128 + ((MH) * 4 + i2) * 16 + rl) * 64 + sw16;          \
        fah[i2] = *(const bf16x8*)(sb + off);                                  \
        fal[i2] = *(const bf16x8*)(sb + 16384 + off);                          \
    }                                                                          \
    _Pragma("unroll")                                                          \
    for (int j2 = 0; j2 < 2; ++j2) {                                           \
        int off = (wc * 64 + ((NH) * 2 + j2) * 16 + rl) * 64 + sw16;           \
        fbh[j2] = *(const bf16x8*)(sb + 32768 + off);                          \
        fbl[j2] = *(const bf16x8*)(sb + 49152 + off);                          \
    }                                                                          \
    EXTRA;                                                                     \
    __builtin_amdgcn_s_setprio(1);                                             \
    _Pragma("unroll")                                                          \
    for (int i2 = 0; i2 < 4; ++i2)                                             \
        _Pragma("unroll")                                                      \
        for (int j2 = 0; j2 < 2; ++j2) {                                       \
            f32x4& a = acc[(MH) * 4 + i2][(NH) * 2 + j2];                      \
            a = __builtin_amdgcn_mfma_f32_16x16x32_bf16(fal[i2], fbh[j2], a, 0, 0, 0); \
            a = __builtin_amdgcn_mfma_f32_16x16x32_bf16(fah[i2], fbl[j2], a, 0, 0, 0); \
            a = __builtin_amdgcn_mfma_f32_16x16x32_bf16(fah[i2], fbh[j2], a, 0, 0, 0); \
        }                                                                      \
    __builtin_amdgcn_s_setprio(0);                                             \
} while (0)

    const int NIT = K >> 5;
    BSet s0, s1;

    // ---- prologue: B0 -> regs -> LDS0; A0 -> LDS0 (async); B1 -> regs ----
    loadB(0, s0);                 // 4 vmem (oldest)
    gloadA(0, smem[0]);           // 4 vmem
    asm volatile("s_waitcnt vmcnt(4)" ::: "memory");   // B0 done
    writeB(smem[0], s0);
    loadB(32, s1);                // 4 vmem
    asm volatile("s_waitcnt vmcnt(4)" ::: "memory");   // A0 done (B1 in flight)
    asm volatile("s_waitcnt lgkmcnt(0)" ::: "memory");
    __builtin_amdgcn_s_barrier();

    // invariant entering tile it: buf[it&1] ready; set[(it+1)&1] holds B(it+1)
    // (in flight); outstanding vmem = B(it+1) only.
    auto tile_body = [&](int it, char* sb, char* sn, BSet& sW, BSet& sL) {
        const bool more1 = (it + 1) < NIT;
        const bool more2 = (it + 2) < NIT;
        PHASE(0, 0, { if (more1) gloadA((it + 1) << 5, sn); });
        asm volatile("" ::: "memory");
        __builtin_amdgcn_s_barrier();

        PHASE(0, 1, { if (more2) loadB((it + 2) << 5, sL); });
        asm volatile("" ::: "memory");
        __builtin_amdgcn_s_barrier();

        PHASE(1, 0, {
            if (more2)      { asm volatile("s_waitcnt vmcnt(8)" ::: "memory"); }
            else if (more1) { asm volatile("s_waitcnt vmcnt(4)" ::: "memory"); }
            if (more1) writeB(sn, sW);
        });
        asm volatile("" ::: "memory");
        __builtin_amdgcn_s_barrier();

        PHASE(1, 1, {});
        if (more2)      { asm volatile("s_waitcnt vmcnt(4)" ::: "memory"); }
        else if (more1) { asm volatile("s_waitcnt vmcnt(0)" ::: "memory"); }
        asm volatile("s_waitcnt lgkmcnt(0)" ::: "memory");
        __builtin_amdgcn_s_barrier();
    };

    for (int it = 0; it < NIT; it += 2) {
        tile_body(it,     smem[0], smem[1], s1, s0);
        tile_body(it + 1, smem[1], smem[0], s0, s1);
    }
#undef PHASE

    // ---- epilogue ----
    #pragma unroll
    for (int i = 0; i < 8; ++i) {
        #pragma unroll
        for (int r = 0; r < 4; ++r) {
            int row = m0 + wr * 128 + i * 16 + kq * 4 + r;
            float sc = 1.0f, bi = 0.0f;
            if (EPI == 1) { sc = gp[row] * BN_RSQRT; bi = bp[row]; }
            #pragma unroll
            for (int j = 0; j < 4; ++j) {
                int col = n0 + wc * 64 + j * 16 + rl;
                float v = acc[i][j][r];
                if (EPI == 1) v = fmaxf(fmaf(v, sc, bi), 0.0f);
                Cb[(long long)row * ldc + col] = v;
            }
        }
    }
}

// ---------------------------------------------------------------------------
// 128-wide split-bf16 MFMA GEMM (gram + lat2t), unchanged from R4
// ---------------------------------------------------------------------------
template <int BN_, int AFMT, int BFMT, int EPI>
__global__ __launch_bounds__(256) void mfma_gemm(
    const void* __restrict__ Ap, const void* __restrict__ Ap2, long long aB, int lda,
    const void* __restrict__ Bp, const void* __restrict__ Bp2, long long bB, int ldb,
    void* __restrict__ Cp, void* __restrict__ Cp2,
    void* __restrict__ Ct, void* __restrict__ Ct2,
    long long cB, int ldc, int ldct,
    int K, const float* __restrict__ gp, const float* __restrict__ bpb)
{
    constexpr int NJ   = BN_ / 32;
    constexpr int BNB  = BN_ * 64;
    constexpr int BUFB = 16384 + BN_ * 128;
    __shared__ __attribute__((aligned(16))) char smem[2][BUFB];

    const int gx = gridDim.x, gy = gridDim.y;
    int nwg = gx * gy * gridDim.z;
    int id = blockIdx.x + gx * (blockIdx.y + gy * blockIdx.z);
    int chunk = nwg >> 3;
    int nid = (id & 7) * chunk + (id >> 3);
    int bx = nid % gx;
    int tmp = nid / gx;
    int by = tmp % gy;
    int bz = tmp / gy;

    const int t  = threadIdx.x;
    const int n0 = bx * BN_;
    const int m0 = by * 128;

    const int ar = t >> 1, ag = t & 1;
    const int af = (ar >> 1) & 3;
    const int as0 = (2 * ag) ^ af, as1 = (2 * ag + 1) ^ af;
    const bool bact = (BN_ == 128) || (t < 2 * BN_);
    const int br = (t >> 1) & (BN_ - 1), bg = t & 1;
    const int bf = (br >> 1) & 3;
    const int bs0 = (2 * bg) ^ bf, bs1 = (2 * bg + 1) ^ bf;

    const int l  = t & 63, w = t >> 6;
    const int wr = w >> 1, wc = w & 1;
    const int rl = l & 15, kq = l >> 4;
    const int sw = kq ^ ((rl >> 1) & 3);
    const int aoff = (wr * 64 + rl) * 64 + sw * 16;
    const int boff = (wc * (BN_ / 2) + rl) * 64 + sw * 16;

    const u16*   Ahp = (const u16*)Ap  + (long long)bz * aB;
    const u16*   Alp = (const u16*)Ap2 + (long long)bz * aB;
    const u16*   Bhp = (const u16*)Bp  + (long long)bz * bB;
    const u16*   Blp = (const u16*)Bp2 + (long long)bz * bB;

    auto loadA = [&](int k0, RegsA& ra) {
        const u16* ph = Ahp + (long long)(m0 + ar) * lda + k0 + ag * 16;
        const u16* pl = Alp + (long long)(m0 + ar) * lda + k0 + ag * 16;
        ra.h[0] = *(const u16x8*)(ph);
        ra.h[1] = *(const u16x8*)(ph + 8);
        ra.l[0] = *(const u16x8*)(pl);
        ra.l[1] = *(const u16x8*)(pl + 8);
    };
    auto loadB = [&](int k0, RegsB& rb) {
        if (!bact) return;
        const u16* ph = Bhp + (long long)(n0 + br) * ldb + k0 + bg * 16;
        const u16* pl = Blp + (long long)(n0 + br) * ldb + k0 + bg * 16;
        rb.h[0] = *(const u16x8*)(ph);
        rb.h[1] = *(const u16x8*)(ph + 8);
        rb.l[0] = *(const u16x8*)(pl);
        rb.l[1] = *(const u16x8*)(pl + 8);
    };
    auto stageWrite = [&](char* sb, RegsA& ra, RegsB& rb) {
        *(u16x8*)(sb + ar * 64 + as0 * 16) = ra.h[0];
        *(u16x8*)(sb + ar * 64 + as1 * 16) = ra.h[1];
        *(u16x8*)(sb + 8192 + ar * 64 + as0 * 16) = ra.l[0];
        *(u16x8*)(sb + 8192 + ar * 64 + as1 * 16) = ra.l[1];
        if (bact) {
            char* sB = sb + 16384;
            *(u16x8*)(sB + br * 64 + bs0 * 16) = rb.h[0];
            *(u16x8*)(sB + br * 64 + bs1 * 16) = rb.h[1];
            *(u16x8*)(sB + BNB + br * 64 + bs0 * 16) = rb.l[0];
            *(u16x8*)(sB + BNB + br * 64 + bs1 * 16) = rb.l[1];
        }
    };

    f32x4 acc[4][NJ];
    #pragma unroll
    for (int i = 0; i < 4; ++i)
        #pragma unroll
        for (int j = 0; j < NJ; ++j)
            acc[i][j] = (f32x4){0.f, 0.f, 0.f, 0.f};

    RegsA a0, a1;
    RegsB b0, b1;
    const int NIT = K >> 5;

    loadA(0, a0); loadB(0, b0);
    stageWrite(smem[0], a0, b0);
    loadA(32, a1); loadB(32, b1);
    asm volatile("s_waitcnt lgkmcnt(0)" ::: "memory");
    __builtin_amdgcn_s_barrier();

    auto step = [&](int it, char* sb, char* sn, RegsA& pa, RegsB& pb,
                    RegsA& qa, RegsB& qb) {
        bf16x8 fah[4], fal[4], fbh[NJ], fbl[NJ];
        #pragma unroll
        for (int i = 0; i < 4; ++i) {
            fah[i] = *(const bf16x8*)(sb + aoff + i * 1024);
            fal[i] = *(const bf16x8*)(sb + 8192 + aoff + i * 1024);
        }
        #pragma unroll
        for (int j = 0; j < NJ; ++j) {
            fbh[j] = *(const bf16x8*)(sb + 16384 + boff + j * 1024);
            fbl[j] = *(const bf16x8*)(sb + 16384 + BNB + boff + j * 1024);
        }
        if (it + 1 < NIT) stageWrite(sn, pa, pb);
        if (it + 2 < NIT) { loadA((it + 2) << 5, qa); loadB((it + 2) << 5, qb); }
        #pragma unroll
        for (int i = 0; i < 4; ++i)
            #pragma unroll
            for (int j = 0; j < NJ; ++j) {
                acc[i][j] = __builtin_amdgcn_mfma_f32_16x16x32_bf16(fal[i], fbh[j], acc[i][j], 0, 0, 0);
                acc[i][j] = __builtin_amdgcn_mfma_f32_16x16x32_bf16(fah[i], fbl[j], acc[i][j], 0, 0, 0);
                acc[i][j] = __builtin_amdgcn_mfma_f32_16x16x32_bf16(fah[i], fbh[j], acc[i][j], 0, 0, 0);
            }
        asm volatile("s_waitcnt lgkmcnt(0)" ::: "memory");
        __builtin_amdgcn_s_barrier();
    };

    for (int it = 0; it < NIT; it += 2) {
        step(it,     smem[0], smem[1], a1, b1, a0, b0);
        step(it + 1, smem[1], smem[0], a0, b0, a1, b1);
    }

    #pragma unroll
    for (int i = 0; i < 4; ++i) {
        #pragma unroll
        for (int r = 0; r < 4; ++r) {
            int row = m0 + wr * 64 + i * 16 + kq * 4 + r;
            #pragma unroll
            for (int j = 0; j < NJ; ++j) {
                int col = n0 + wc * (BN_ / 2) + j * 16 + rl;
                float v = acc[i][j][r];
                if constexpr (EPI == 0) {
                    ((float*)Cp + (long long)bz * cB)[(long long)row * ldc + col] = v;
                } else {
                    unsigned short hh, ll; split2(v, hh, ll);
                    ((u16*)Cp  + (long long)bz * cB)[(long long)row * ldc + col] = hh;
                    ((u16*)Cp2 + (long long)bz * cB)[(long long)row * ldc + col] = ll;
                }
            }
        }
    }
}

// ---------------------------------------------------------------------------
// Row L2-norm over C of Y[B][D][C] fp32 -> in-place K'-PERMUTED split planes:
// row layout [hi 2048][lo 2048] (lda=4096), k' = (c&1)*1024 + (c>>1).
// ---------------------------------------------------------------------------
__global__ __launch_bounds__(256) void rownorm_split_perm_k(float* __restrict__ Y) {
    int d = blockIdx.x, b = blockIdx.y, t = threadIdx.x;
    float* row = Y + ((long long)b * DD + d) * CC;
    float4 v0 = ((const float4*)row)[2 * t];
    float4 v1 = ((const float4*)row)[2 * t + 1];
    float s = v0.x * v0.x + v0.y * v0.y + v0.z * v0.z + v0.w * v0.w
            + v1.x * v1.x + v1.y * v1.y + v1.z * v1.z + v1.w * v1.w;
    for (int off = 32; off > 0; off >>= 1) s += __shfl_down(s, off, 64);
    __shared__ float wsum[4];
    __shared__ float ivs;
    int lane = t & 63, w = t >> 6;
    if (lane == 0) wsum[w] = s;
    __syncthreads();
    if (t == 0) ivs = 1.0f / fmaxf(sqrtf(wsum[0] + wsum[1] + wsum[2] + wsum[3]), 1e-12f);
    __syncthreads();
    float iv = ivs;
    float xs[8] = {v0.x * iv, v0.y * iv, v0.z * iv, v0.w * iv,
                   v1.x * iv, v1.y * iv, v1.z * iv, v1.w * iv};
    u16x4 he, ho, le, lo4;
    #pragma unroll
    for (int j = 0; j < 4; ++j) {
        unsigned short hh, ll;
        split2(xs[2 * j], hh, ll);       he[j] = hh; le[j] = ll;   // even c -> k' = c/2
        split2(xs[2 * j + 1], hh, ll);   ho[j] = hh; lo4[j] = ll;  // odd  c -> k' = 1024 + c/2
    }
    u16* hi = (u16*)row;
    *(u16x4*)(hi + 4 * t) = he;
    *(u16x4*)(hi + 1024 + 4 * t) = ho;
    *(u16x4*)(hi + 2048 + 4 * t) = le;
    *(u16x4*)(hi + 3072 + 4 * t) = lo4;
}

// ---------------------------------------------------------------------------
__global__ __launch_bounds__(256) void colnorm_k(const float* __restrict__ Yl,
                                                 float* __restrict__ rsc) {
    int b = blockIdx.y;
    int c = blockIdx.x * 256 + threadIdx.x;
    const float* base = Yl + (long long)b * DD * CC + c;
    float s = 0.0f;
    for (int d = 0; d < DD; ++d) { float v = base[(long long)d * CC]; s += v * v; }
    rsc[(long long)b * CC + c] = 1.0f / fmaxf(sqrtf(s), 1e-12f);
}

// ---------------------------------------------------------------------------
// transpose + column-scale + split: Yl[B][D][C] -> Ylt planes [B][C][D]
// ---------------------------------------------------------------------------
__global__ __launch_bounds__(256) void trans_split_k(const float* __restrict__ in,
                                                     const float* __restrict__ scale,
                                                     u16* __restrict__ hi, u16* __restrict__ lo) {
    __shared__ float tile[32][33];
    int s0 = blockIdx.x * 32, r0 = blockIdx.y * 32, b = blockIdx.z;
    const float* inb = in + (long long)b * DD * CC;
    int tx = threadIdx.x & 31, ty = threadIdx.x >> 5;
    for (int i = ty; i < 32; i += 8)
        tile[i][tx] = inb[(long long)(r0 + i) * CC + s0 + tx];
    __syncthreads();
    for (int i = ty; i < 32; i += 8) {
        float v = tile[tx][i] * scale[(long long)b * CC + s0 + i];
        unsigned short hh, ll; split2(v, hh, ll);
        long long o = (long long)b * DD * CC + (long long)(s0 + i) * DD + r0 + tx;
        hi[o] = hh; lo[o] = ll;
    }
}

// ---------------------------------------------------------------------------
// Sum 4 K-split parts of latent [B][D][HW] -> split planes + transposed planes
// ---------------------------------------------------------------------------
__global__ __launch_bounds__(256) void latreduce_k(const float* __restrict__ parts,
                                                   u16* __restrict__ hi, u16* __restrict__ lo,
                                                   u16* __restrict__ thi, u16* __restrict__ tlo) {
    __shared__ float tile[32][33];
    int h0 = blockIdx.x * 32, d0 = blockIdx.y * 32, b = blockIdx.z;
    const long long sL = (long long)DD * HWW;
    const long long ps = (long long)BB * sL;
    const float* base = parts + (long long)b * sL;
    int tx = threadIdx.x & 31, ty = threadIdx.x >> 5;
    for (int i = ty; i < 32; i += 8) {
        long long o = (long long)(d0 + i) * HWW + h0 + tx;
        float s = base[o] + base[o + ps] + base[o + 2 * ps] + base[o + 3 * ps];
        tile[i][tx] = s;
        unsigned short hh, ll; split2(s, hh, ll);
        long long od = (long long)b * sL + o;
        hi[od] = hh; lo[od] = ll;
    }
    __syncthreads();
    for (int i = ty; i < 32; i += 8) {
        float v = tile[tx][i];
        unsigned short hh, ll; split2(v, hh, ll);
        long long ot = (long long)b * sL + (long long)(h0 + i) * DD + d0 + tx;
        thi[ot] = hh; tlo[ot] = ll;
    }
}

// ---------------------------------------------------------------------------
__global__ __launch_bounds__(256) void latnorm_k(const float* __restrict__ G,
                                                 float* __restrict__ rs) {
    int i = blockIdx.x * 256 + threadIdx.x;
    int b = i >> 8, d = i & 255;
    float v = G[((long long)b * DD + d) * DD + d];
    rs[i] = 1.0f / fmaxf(sqrtf(v), 1e-12f);
}

// softmax over gram rows -> aff hi/lo planes
__global__ __launch_bounds__(256) void softmax_k(const float* __restrict__ G,
                                                 const float* __restrict__ rs,
                                                 u16* __restrict__ affHi,
                                                 u16* __restrict__ affLo) {
    int d = blockIdx.x, b = blockIdx.y;
    const float* row = G + ((long long)b * DD + d) * DD;
    const float* rsb = rs + (long long)b * DD;
    int t = threadIdx.x;
    float lg = row[t] * rsb[d] * rsb[t];

    float m = lg;
    for (int off = 32; off > 0; off >>= 1) m = fmaxf(m, __shfl_down(m, off, 64));
    __shared__ float wsm[4];
    __shared__ float bm, bs;
    int lane = t & 63, w = t >> 6;
    if (lane == 0) wsm[w] = m;
    __syncthreads();
    if (t == 0) bm = fmaxf(fmaxf(wsm[0], wsm[1]), fmaxf(wsm[2], wsm[3]));
    __syncthreads();
    float e = expf(lg - bm);
    float s = e;
    for (int off = 32; off > 0; off >>= 1) s += __shfl_down(s, off, 64);
    if (lane == 0) wsm[w] = s;
    __syncthreads();
    if (t == 0) bs = wsm[0] + wsm[1] + wsm[2] + wsm[3];
    __syncthreads();
    float v = e / bs;
    unsigned short hh, ll; split2(v, hh, ll);
    long long o = ((long long)b * DD + d) * DD + t;
    affHi[o] = hh; affLo[o] = ll;
}

// ---------------------------------------------------------------------------
extern "C" void kernel_launch(void* const* d_in, const int* in_sizes, int n_in,
                              void* d_out, int out_size, void* d_ws, size_t ws_size,
                              hipStream_t stream) {
    const float* v2l   = (const float*)d_in[0];
    const float* l2v   = (const float*)d_in[1];
    const float* w_v2l = (const float*)d_in[2];
    const float* g_v2l = (const float*)d_in[3];
    const float* b_v2l = (const float*)d_in[4];
    const float* w_l2v = (const float*)d_in[5];
    const float* g_l2v = (const float*)d_in[6];
    const float* b_l2v = (const float*)d_in[7];
    float* out = (float*)d_out;

    char* W = (char*)d_ws;
    float* Yv     = (float*)(W + 0);            // 32MB fp32 -> in-place permuted planes
    float* Yl     = (float*)(W + 33554432);     // 32MB
    u16*   YltHi  = (u16*)(W + 67108864);       // 16MB
    u16*   YltLo  = (u16*)(W + 83886080);       // 16MB
    u16*   latHi  = (u16*)(W + 100663296);      //  8MB
    u16*   latLo  = (u16*)(W + 109051904);      //  8MB
    u16*   latTHi = (u16*)(W + 117440512);      //  8MB
    u16*   latTLo = (u16*)(W + 125829120);      //  8MB
    u16*   l2tHi  = (u16*)(W + 134217728);      //  8MB
    u16*   l2tLo  = (u16*)(W + 142606336);      //  8MB
    float* gram   = (float*)(W + 150994944);    //  4MB
    float* rs     = (float*)(W + 155189248);
    float* rsc    = (float*)(W + 155205632);
    u16*   affHi  = (u16*)(W + 155336704);      //  2MB
    u16*   affLo  = (u16*)(W + 157433856);      //  2MB
    u16*   WvHi   = (u16*)(W + 159531008);      //  512KB each
    u16*   WvLo   = WvHi + 262144;
    u16*   WlHi   = WvLo + 262144;
    u16*   WlLo   = WlHi + 262144;

    // K-split latent parts (4 x [B][D][HW] fp32 = 64MB) live in d_out scratch
    float* latPart = (float*)d_out;

    const long long sY   = (long long)DD * CC;     // 524288
    const long long sL   = (long long)DD * HWW;    // 262144
    const long long sG   = (long long)DD * DD;     // 65536
    const long long sX   = (long long)CC * HWW;    // 2097152
    const long long sYp  = (long long)DD * 4096;   // in-place plane stride (u16)

    // weights -> planes
    split_k<<<128, 256, 0, stream>>>(w_v2l, WvHi, WvLo, 32768);
    split_k<<<128, 256, 0, stream>>>(w_l2v, WlHi, WlLo, 32768);

    // G1+G2 fused: Yv/Yl = relu(sc*(W . X^T)+b)  [D=256 x C=2048], K=1024
    gemm8<0, 1, 1, 1><<<dim3(CC / 256, 1, 32), 512, 0, stream>>>(
        WvHi, WvLo, WlHi, WlLo, 0, HWW,
        v2l, nullptr, l2v, nullptr, sX, HWW,
        Yv, Yl, sY, 0, CC, HWW,
        g_v2l, b_v2l, g_l2v, b_l2v);

    rownorm_split_perm_k<<<dim3(DD, BB), 256, 0, stream>>>(Yv);
    colnorm_k<<<dim3(CC / 256, BB), 256, 0, stream>>>(Yl, rsc);
    trans_split_k<<<dim3(CC / 32, DD / 32, BB), 256, 0, stream>>>(Yl, rsc, YltHi, YltLo);

    // G3 (K-split x4): latent parts = Yvn(k') . B'(k')^T   [D=256 x HW=1024]
    gemm8<3, 0, 0, 4><<<dim3(HWW / 256, 1, 64), 512, 0, stream>>>(
        (const u16*)Yv, (const u16*)Yv + 2048, nullptr, nullptr, sYp, 4096,
        v2l, nullptr, nullptr, nullptr, sX, HWW,
        latPart, nullptr, sL, (long long)BB * sL, HWW, 512,
        nullptr, nullptr, nullptr, nullptr);

    latreduce_k<<<dim3(HWW / 32, DD / 32, BB), 256, 0, stream>>>(
        latPart, latHi, latLo, latTHi, latTLo);

    // gram = latent . latent^T  (plane MFMA, fp32 out)
    mfma_gemm<64, 1, 1, 0><<<dim3(4, 2, BB), 256, 0, stream>>>(
        latHi, latLo, sL, HWW, latHi, latLo, sL, HWW,
        gram, nullptr, nullptr, nullptr, sG, DD, 0, HWW, nullptr, nullptr);

    latnorm_k<<<dim3(BB * DD / 256), 256, 0, stream>>>(gram, rs);
    softmax_k<<<dim3(DD, BB), 256, 0, stream>>>(gram, rs, affHi, affLo);

    // lat2t = latentT . aff^T  [HW,D] -> planes
    mfma_gemm<128, 1, 1, 3><<<dim3(2, 8, BB), 256, 0, stream>>>(
        latTHi, latTLo, sL, DD, affHi, affLo, sG, DD,
        l2tHi, l2tLo, nullptr, nullptr, sL, DD, 0, DD, nullptr, nullptr);

    // G6: out = Ylt . l2t^T  [C=2048 x HW=1024], K=256
    gemm8<1, 0, 0, 1><<<dim3(HWW / 256, CC / 256, BB), 512, 0, stream>>>(
        YltHi, YltLo, nullptr, nullptr, sY, DD,
        l2tHi, l2tLo, nullptr, nullptr, sL, DD,
        out, nullptr, sX, 0, HWW, DD,
        nullptr, nullptr, nullptr, nullptr);
}

// Round 7
// 380.795 us; speedup vs baseline: 1.1292x; 1.1292x over previous
//
#include <hip/hip_runtime.h>
#include <hip/hip_bf16.h>

#define BB 16
#define CC 2048
#define HWW 1024
#define DD 256
#define BN_RSQRT 0.9999950000374997f

typedef short bf16x8 __attribute__((ext_vector_type(8)));
typedef float f32x4 __attribute__((ext_vector_type(4)));
typedef unsigned short u16x8 __attribute__((ext_vector_type(8)));
typedef unsigned short u16x4 __attribute__((ext_vector_type(4)));
typedef unsigned short u16;

typedef __attribute__((address_space(1))) const unsigned GU;
typedef __attribute__((address_space(3))) unsigned LU;
__device__ __forceinline__ void gload16(const void* g, void* l) {
    __builtin_amdgcn_global_load_lds((GU*)g, (LU*)l, 16, 0, 0);
}

// ---- bf16 split helpers ----
__device__ __forceinline__ unsigned short f2bf(float x) {
    unsigned u = __builtin_bit_cast(unsigned, x);
    unsigned r = u + 0x7FFFu + ((u >> 16) & 1u);
    return (unsigned short)(r >> 16);
}
__device__ __forceinline__ float bf2f(unsigned short h) {
    unsigned u = ((unsigned)h) << 16;
    return __builtin_bit_cast(float, u);
}
__device__ __forceinline__ void split2(float x, unsigned short& hi, unsigned short& lo) {
    hi = f2bf(x);
    lo = f2bf(x - bf2f(hi));
}
// cheap variant for frag-read time: RNE hi, truncated lo
__device__ __forceinline__ void split2t(float x, unsigned short& hi, unsigned short& lo) {
    hi = f2bf(x);
    float d = x - bf2f(hi);
    lo = (unsigned short)(__builtin_bit_cast(unsigned, d) >> 16);
}

struct RegsA { u16x8 h[2]; u16x8 l[2]; };
struct RegsB { u16x8 h[2]; u16x8 l[2]; };

// ---------------------------------------------------------------------------
// split fp32 -> hi/lo bf16 planes (weights only)
// ---------------------------------------------------------------------------
__global__ __launch_bounds__(256) void split_k(const float* __restrict__ in,
                                               u16* __restrict__ hi, u16* __restrict__ lo,
                                               long long n8) {
    long long i = (long long)blockIdx.x * 256 + threadIdx.x;
    if (i >= n8) return;
    const float4* p = (const float4*)in + i * 2;
    float4 a = p[0], b = p[1];
    float xs[8] = {a.x, a.y, a.z, a.w, b.x, b.y, b.z, b.w};
    u16x8 h, l;
    #pragma unroll
    for (int j = 0; j < 8; ++j) { unsigned short hh, ll; split2(xs[j], hh, ll); h[j] = hh; l[j] = ll; }
    *(u16x8*)(hi + i * 8) = h;
    *(u16x8*)(lo + i * 8) = l;
}

// ---------------------------------------------------------------------------
// gemm8 v3 — all-gload-lds split-bf16 MFMA GEMM (NT): C = sum_k A[m][k]B[n][k]
// 256x256 tile, BK=32, 8 waves, dbuf 2x64KB LDS, NO staging registers:
// both operands via global_load_lds issued one full tile ahead; boundary
// vmcnt(0) drains loads issued ~a tile earlier (near-free).
// A: bf16 hi/lo planes (16KB+16KB per tile, XOR-swizzled source).
// BF: 0 = B fp32 rows [n][k] staged raw (32KB), split to hi/lo at frag read.
//     1 = B bf16 hi/lo planes (16+16KB).
// Fragments read ONCE per K-tile (A per-quadrant, B once), 2 MFMA bursts of
// 48 with split terms interleaved by term. EPI: 0 fp32, 1 relu(g*sc*x+b).
// FUSE2: grid.z=32, op=z>>4.  KS: K-split, grid.z=16*KS.
// ---------------------------------------------------------------------------
template <int BF, int EPI, int FUSE2, int KS>
__global__ __launch_bounds__(512, 2) void gemm8(
    const u16* __restrict__ Ah0, const u16* __restrict__ Al0,
    const u16* __restrict__ Ah1, const u16* __restrict__ Al1,
    long long aB, int lda,
    const void* __restrict__ B0a, const void* __restrict__ B0b,
    const void* __restrict__ B1a, const void* __restrict__ B1b,
    long long bB, int ldb,
    float* __restrict__ C0, float* __restrict__ C1,
    long long cB, long long kB, int ldc,
    int K,
    const float* __restrict__ g0, const float* __restrict__ bb0,
    const float* __restrict__ g1, const float* __restrict__ bb1)
{
    __shared__ __attribute__((aligned(16))) char smem[2][65536];

    // bijective XCD-chunk swizzle (nwg % 8 == 0 for all grids used)
    const int gx = gridDim.x, gy = gridDim.y;
    int nwg = gx * gy * gridDim.z;
    int id = blockIdx.x + gx * (blockIdx.y + gy * blockIdx.z);
    int chunk = nwg >> 3;
    int nid = (id & 7) * chunk + (id >> 3);
    int bx = nid % gx;
    int tmp = nid / gx;
    int by = tmp % gy;
    int bz = tmp / gy;

    const int t = threadIdx.x;
    const int n0 = bx * 256, m0 = by * 256;

    int op = 0, batch, kz = 0;
    if constexpr (FUSE2) { op = bz >> 4; batch = bz & 15; }
    else if constexpr (KS > 1) { batch = bz / KS; kz = bz - batch * KS; }
    else { batch = bz; }
    const int koffA = kz * K;

    const u16* Ahp = (op ? Ah1 : Ah0) + (long long)batch * aB + koffA;
    const u16* Alp = (op ? Al1 : Al0) + (long long)batch * aB + koffA;
    const float* Bf = nullptr;
    const u16* Bh = nullptr;
    const u16* Bl = nullptr;
    if constexpr (BF == 0) {
        Bf = (const float*)(op ? B1a : B0a) + (long long)batch * bB;
        // k'-parity base shift (G3); zero when koffA==0
        Bf += ((long long)(koffA >> 10)) * 1024 * ldb + (koffA & 1023);
    } else {
        Bh = (const u16*)(op ? B1a : B0a) + (long long)batch * bB;
        Bl = (const u16*)(op ? B1b : B0b) + (long long)batch * bB;
    }
    float* Cb = ((EPI == 1 && FUSE2) ? (op ? C1 : C0) : C0)
              + (long long)batch * cB + (long long)kz * kB;
    const float* gp = op ? g1 : g0;
    const float* bp = op ? bb1 : bb0;

    // ---- gload staging coords (inverse-swizzled SOURCE, linear LDS dest) ----
    const int arow = t >> 2;                          // A rows 0..127 (+128)
    const int aslt = (t & 3) ^ ((t >> 3) & 3);        // A source slot (16B=8 u16)
    const int brow = t >> 3;                          // B fp32 rows 0..63 (+64k)
    const int bslt = (t & 7) ^ ((t >> 3) & 7);        // B source slot (16B=4 f32)

    // ---- fragment coords ----
    const int l = t & 63, w = t >> 6;
    const int wr = w >> 2, wc = w & 3;
    const int rl = l & 15, kq = l >> 4;
    const int fsw = (kq ^ ((rl >> 1) & 3)) * 16;      // plane frag slot-bytes

    f32x4 acc[8][4];
    #pragma unroll
    for (int i = 0; i < 8; ++i)
        #pragma unroll
        for (int j = 0; j < 4; ++j)
            acc[i][j] = (f32x4){0.f, 0.f, 0.f, 0.f};

    auto gstage = [&](int k0, char* sn) {
        const u16* pa = Ahp + (long long)(m0 + arow) * lda + k0 + aslt * 8;
        gload16(pa,                        sn + t * 16);
        gload16(pa + (long long)128 * lda, sn + 8192 + t * 16);
        const u16* pl = Alp + (long long)(m0 + arow) * lda + k0 + aslt * 8;
        gload16(pl,                        sn + 16384 + t * 16);
        gload16(pl + (long long)128 * lda, sn + 24576 + t * 16);
        if constexpr (BF == 0) {
            const float* pb = Bf + (long long)(n0 + brow) * ldb + k0 + bslt * 4;
            #pragma unroll
            for (int kk = 0; kk < 4; ++kk)
                gload16(pb + (long long)(64 * kk) * ldb,
                        sn + 32768 + kk * 8192 + t * 16);
        } else {
            const u16* pbh = Bh + (long long)(n0 + arow) * ldb + k0 + aslt * 8;
            gload16(pbh,                        sn + 32768 + t * 16);
            gload16(pbh + (long long)128 * ldb, sn + 40960 + t * 16);
            const u16* pbl = Bl + (long long)(n0 + arow) * ldb + k0 + aslt * 8;
            gload16(pbl,                        sn + 49152 + t * 16);
            gload16(pbl + (long long)128 * ldb, sn + 57344 + t * 16);
        }
    };

    auto readA = [&](const char* sb, int q, bf16x8* fah, bf16x8* fal) {
        #pragma unroll
        for (int i2 = 0; i2 < 4; ++i2) {
            int row = wr * 128 + (q * 4 + i2) * 16 + rl;
            int off = row * 64 + fsw;
            fah[i2] = *(const bf16x8*)(sb + off);
            fal[i2] = *(const bf16x8*)(sb + 16384 + off);
        }
    };
    auto readB = [&](const char* sb, bf16x8* fbh, bf16x8* fbl) {
        #pragma unroll
        for (int j = 0; j < 4; ++j) {
            int row = wc * 64 + j * 16 + rl;
            if constexpr (BF == 0) {
                const char* p = sb + 32768 + row * 128;
                int g = rl & 7;
                float4 x0 = *(const float4*)(p + ((2 * kq) ^ g) * 16);
                float4 x1 = *(const float4*)(p + ((2 * kq + 1) ^ g) * 16);
                float xs[8] = {x0.x, x0.y, x0.z, x0.w, x1.x, x1.y, x1.z, x1.w};
                u16x8 h, lo;
                #pragma unroll
                for (int e = 0; e < 8; ++e) {
                    unsigned short hh, ll; split2t(xs[e], hh, ll);
                    h[e] = hh; lo[e] = ll;
                }
                fbh[j] = __builtin_bit_cast(bf16x8, h);
                fbl[j] = __builtin_bit_cast(bf16x8, lo);
            } else {
                int off = row * 64 + fsw;
                fbh[j] = *(const bf16x8*)(sb + 32768 + off);
                fbl[j] = *(const bf16x8*)(sb + 49152 + off);
            }
        }
    };

    const int NIT = K >> 5;

    // prologue: stage tile 0, drain, barrier
    gstage(0, smem[0]);
    asm volatile("s_waitcnt vmcnt(0)" ::: "memory");
    __builtin_amdgcn_s_barrier();

    for (int it = 0; it < NIT; ++it) {
        char* sb = smem[it & 1];
        char* sn = smem[(it + 1) & 1];
        if (it + 1 < NIT) gstage((it + 1) << 5, sn);

        bf16x8 fbh[4], fbl[4], fah[4], fal[4];
        readB(sb, fbh, fbl);
        readA(sb, 0, fah, fal);
        __builtin_amdgcn_s_barrier();

        __builtin_amdgcn_s_setprio(1);
        #pragma unroll
        for (int i2 = 0; i2 < 4; ++i2)
            #pragma unroll
            for (int j = 0; j < 4; ++j)
                acc[i2][j] = __builtin_amdgcn_mfma_f32_16x16x32_bf16(fal[i2], fbh[j], acc[i2][j], 0, 0, 0);
        #pragma unroll
        for (int i2 = 0; i2 < 4; ++i2)
            #pragma unroll
            for (int j = 0; j < 4; ++j)
                acc[i2][j] = __builtin_amdgcn_mfma_f32_16x16x32_bf16(fah[i2], fbl[j], acc[i2][j], 0, 0, 0);
        #pragma unroll
        for (int i2 = 0; i2 < 4; ++i2)
            #pragma unroll
            for (int j = 0; j < 4; ++j)
                acc[i2][j] = __builtin_amdgcn_mfma_f32_16x16x32_bf16(fah[i2], fbh[j], acc[i2][j], 0, 0, 0);
        __builtin_amdgcn_s_setprio(0);
        __builtin_amdgcn_s_barrier();

        readA(sb, 1, fah, fal);
        __builtin_amdgcn_s_setprio(1);
        #pragma unroll
        for (int i2 = 0; i2 < 4; ++i2)
            #pragma unroll
            for (int j = 0; j < 4; ++j)
                acc[4 + i2][j] = __builtin_amdgcn_mfma_f32_16x16x32_bf16(fal[i2], fbh[j], acc[4 + i2][j], 0, 0, 0);
        #pragma unroll
        for (int i2 = 0; i2 < 4; ++i2)
            #pragma unroll
            for (int j = 0; j < 4; ++j)
                acc[4 + i2][j] = __builtin_amdgcn_mfma_f32_16x16x32_bf16(fah[i2], fbl[j], acc[4 + i2][j], 0, 0, 0);
        #pragma unroll
        for (int i2 = 0; i2 < 4; ++i2)
            #pragma unroll
            for (int j = 0; j < 4; ++j)
                acc[4 + i2][j] = __builtin_amdgcn_mfma_f32_16x16x32_bf16(fah[i2], fbh[j], acc[4 + i2][j], 0, 0, 0);
        __builtin_amdgcn_s_setprio(0);
        asm volatile("s_waitcnt vmcnt(0)" ::: "memory");
        __builtin_amdgcn_s_barrier();
    }

    // epilogue
    #pragma unroll
    for (int i = 0; i < 8; ++i) {
        #pragma unroll
        for (int r = 0; r < 4; ++r) {
            int row = m0 + wr * 128 + i * 16 + kq * 4 + r;
            float sc = 1.0f, bi = 0.0f;
            if (EPI == 1) { sc = gp[row] * BN_RSQRT; bi = bp[row]; }
            #pragma unroll
            for (int j = 0; j < 4; ++j) {
                int col = n0 + wc * 64 + j * 16 + rl;
                float v = acc[i][j][r];
                if (EPI == 1) v = fmaxf(fmaf(v, sc, bi), 0.0f);
                Cb[(long long)row * ldc + col] = v;
            }
        }
    }
}

// ---------------------------------------------------------------------------
// 128-wide split-bf16 MFMA GEMM (gram + lat2t), plane inputs only
// ---------------------------------------------------------------------------
template <int BN_, int EPI>
__global__ __launch_bounds__(256) void mfma_gemm(
    const void* __restrict__ Ap, const void* __restrict__ Ap2, long long aB, int lda,
    const void* __restrict__ Bp, const void* __restrict__ Bp2, long long bB, int ldb,
    void* __restrict__ Cp, void* __restrict__ Cp2,
    long long cB, int ldc, int K)
{
    constexpr int NJ   = BN_ / 32;
    constexpr int BNB  = BN_ * 64;
    constexpr int BUFB = 16384 + BN_ * 128;
    __shared__ __attribute__((aligned(16))) char smem[2][BUFB];

    const int gx = gridDim.x, gy = gridDim.y;
    int nwg = gx * gy * gridDim.z;
    int id = blockIdx.x + gx * (blockIdx.y + gy * blockIdx.z);
    int chunk = nwg >> 3;
    int nid = (id & 7) * chunk + (id >> 3);
    int bx = nid % gx;
    int tmp = nid / gx;
    int by = tmp % gy;
    int bz = tmp / gy;

    const int t  = threadIdx.x;
    const int n0 = bx * BN_;
    const int m0 = by * 128;

    const int ar = t >> 1, ag = t & 1;
    const int af = (ar >> 1) & 3;
    const int as0 = (2 * ag) ^ af, as1 = (2 * ag + 1) ^ af;
    const bool bact = (BN_ == 128) || (t < 2 * BN_);
    const int br = (t >> 1) & (BN_ - 1), bg = t & 1;
    const int bf = (br >> 1) & 3;
    const int bs0 = (2 * bg) ^ bf, bs1 = (2 * bg + 1) ^ bf;

    const int l  = t & 63, w = t >> 6;
    const int wr = w >> 1, wc = w & 1;
    const int rl = l & 15, kq = l >> 4;
    const int sw = kq ^ ((rl >> 1) & 3);
    const int aoff = (wr * 64 + rl) * 64 + sw * 16;
    const int boff = (wc * (BN_ / 2) + rl) * 64 + sw * 16;

    const u16* Ahp = (const u16*)Ap  + (long long)bz * aB;
    const u16* Alp = (const u16*)Ap2 + (long long)bz * aB;
    const u16* Bhp = (const u16*)Bp  + (long long)bz * bB;
    const u16* Blp = (const u16*)Bp2 + (long long)bz * bB;

    auto loadA = [&](int k0, RegsA& ra) {
        const u16* ph = Ahp + (long long)(m0 + ar) * lda + k0 + ag * 16;
        const u16* pl = Alp + (long long)(m0 + ar) * lda + k0 + ag * 16;
        ra.h[0] = *(const u16x8*)(ph);
        ra.h[1] = *(const u16x8*)(ph + 8);
        ra.l[0] = *(const u16x8*)(pl);
        ra.l[1] = *(const u16x8*)(pl + 8);
    };
    auto loadB = [&](int k0, RegsB& rb) {
        if (!bact) return;
        const u16* ph = Bhp + (long long)(n0 + br) * ldb + k0 + bg * 16;
        const u16* pl = Blp + (long long)(n0 + br) * ldb + k0 + bg * 16;
        rb.h[0] = *(const u16x8*)(ph);
        rb.h[1] = *(const u16x8*)(ph + 8);
        rb.l[0] = *(const u16x8*)(pl);
        rb.l[1] = *(const u16x8*)(pl + 8);
    };
    auto stageWrite = [&](char* sb, RegsA& ra, RegsB& rb) {
        *(u16x8*)(sb + ar * 64 + as0 * 16) = ra.h[0];
        *(u16x8*)(sb + ar * 64 + as1 * 16) = ra.h[1];
        *(u16x8*)(sb + 8192 + ar * 64 + as0 * 16) = ra.l[0];
        *(u16x8*)(sb + 8192 + ar * 64 + as1 * 16) = ra.l[1];
        if (bact) {
            char* sB = sb + 16384;
            *(u16x8*)(sB + br * 64 + bs0 * 16) = rb.h[0];
            *(u16x8*)(sB + br * 64 + bs1 * 16) = rb.h[1];
            *(u16x8*)(sB + BNB + br * 64 + bs0 * 16) = rb.l[0];
            *(u16x8*)(sB + BNB + br * 64 + bs1 * 16) = rb.l[1];
        }
    };

    f32x4 acc[4][NJ];
    #pragma unroll
    for (int i = 0; i < 4; ++i)
        #pragma unroll
        for (int j = 0; j < NJ; ++j)
            acc[i][j] = (f32x4){0.f, 0.f, 0.f, 0.f};

    RegsA a0, a1;
    RegsB b0, b1;
    const int NIT = K >> 5;

    loadA(0, a0); loadB(0, b0);
    stageWrite(smem[0], a0, b0);
    loadA(32, a1); loadB(32, b1);
    asm volatile("s_waitcnt lgkmcnt(0)" ::: "memory");
    __builtin_amdgcn_s_barrier();

    auto step = [&](int it, char* sb, char* sn, RegsA& pa, RegsB& pb,
                    RegsA& qa, RegsB& qb) {
        bf16x8 fah[4], fal[4], fbh[NJ], fbl[NJ];
        #pragma unroll
        for (int i = 0; i < 4; ++i) {
            fah[i] = *(const bf16x8*)(sb + aoff + i * 1024);
            fal[i] = *(const bf16x8*)(sb + 8192 + aoff + i * 1024);
        }
        #pragma unroll
        for (int j = 0; j < NJ; ++j) {
            fbh[j] = *(const bf16x8*)(sb + 16384 + boff + j * 1024);
            fbl[j] = *(const bf16x8*)(sb + 16384 + BNB + boff + j * 1024);
        }
        if (it + 1 < NIT) stageWrite(sn, pa, pb);
        if (it + 2 < NIT) { loadA((it + 2) << 5, qa); loadB((it + 2) << 5, qb); }
        #pragma unroll
        for (int i = 0; i < 4; ++i)
            #pragma unroll
            for (int j = 0; j < NJ; ++j) {
                acc[i][j] = __builtin_amdgcn_mfma_f32_16x16x32_bf16(fal[i], fbh[j], acc[i][j], 0, 0, 0);
                acc[i][j] = __builtin_amdgcn_mfma_f32_16x16x32_bf16(fah[i], fbl[j], acc[i][j], 0, 0, 0);
                acc[i][j] = __builtin_amdgcn_mfma_f32_16x16x32_bf16(fah[i], fbh[j], acc[i][j], 0, 0, 0);
            }
        asm volatile("s_waitcnt lgkmcnt(0)" ::: "memory");
        __builtin_amdgcn_s_barrier();
    };

    for (int it = 0; it < NIT; it += 2) {
        step(it,     smem[0], smem[1], a1, b1, a0, b0);
        step(it + 1, smem[1], smem[0], a0, b0, a1, b1);
    }

    #pragma unroll
    for (int i = 0; i < 4; ++i) {
        #pragma unroll
        for (int r = 0; r < 4; ++r) {
            int row = m0 + wr * 64 + i * 16 + kq * 4 + r;
            #pragma unroll
            for (int j = 0; j < NJ; ++j) {
                int col = n0 + wc * (BN_ / 2) + j * 16 + rl;
                float v = acc[i][j][r];
                if constexpr (EPI == 0) {
                    ((float*)Cp + (long long)bz * cB)[(long long)row * ldc + col] = v;
                } else {
                    unsigned short hh, ll; split2(v, hh, ll);
                    ((u16*)Cp  + (long long)bz * cB)[(long long)row * ldc + col] = hh;
                    ((u16*)Cp2 + (long long)bz * cB)[(long long)row * ldc + col] = ll;
                }
            }
        }
    }
}

// ---------------------------------------------------------------------------
// Row L2-norm over C of Y[B][D][C] fp32 -> in-place K'-PERMUTED split planes:
// row layout [hi 2048][lo 2048] (lda=4096), k' = (c&1)*1024 + (c>>1).
// ---------------------------------------------------------------------------
__global__ __launch_bounds__(256) void rownorm_split_perm_k(float* __restrict__ Y) {
    int d = blockIdx.x, b = blockIdx.y, t = threadIdx.x;
    float* row = Y + ((long long)b * DD + d) * CC;
    float4 v0 = ((const float4*)row)[2 * t];
    float4 v1 = ((const float4*)row)[2 * t + 1];
    float s = v0.x * v0.x + v0.y * v0.y + v0.z * v0.z + v0.w * v0.w
            + v1.x * v1.x + v1.y * v1.y + v1.z * v1.z + v1.w * v1.w;
    for (int off = 32; off > 0; off >>= 1) s += __shfl_down(s, off, 64);
    __shared__ float wsum[4];
    __shared__ float ivs;
    int lane = t & 63, w = t >> 6;
    if (lane == 0) wsum[w] = s;
    __syncthreads();
    if (t == 0) ivs = 1.0f / fmaxf(sqrtf(wsum[0] + wsum[1] + wsum[2] + wsum[3]), 1e-12f);
    __syncthreads();
    float iv = ivs;
    float xs[8] = {v0.x * iv, v0.y * iv, v0.z * iv, v0.w * iv,
                   v1.x * iv, v1.y * iv, v1.z * iv, v1.w * iv};
    u16x4 he, ho, le, lo4;
    #pragma unroll
    for (int j = 0; j < 4; ++j) {
        unsigned short hh, ll;
        split2(xs[2 * j], hh, ll);       he[j] = hh; le[j] = ll;
        split2(xs[2 * j + 1], hh, ll);   ho[j] = hh; lo4[j] = ll;
    }
    u16* hi = (u16*)row;
    *(u16x4*)(hi + 4 * t) = he;
    *(u16x4*)(hi + 1024 + 4 * t) = ho;
    *(u16x4*)(hi + 2048 + 4 * t) = le;
    *(u16x4*)(hi + 3072 + 4 * t) = lo4;
}

// ---------------------------------------------------------------------------
__global__ __launch_bounds__(256) void colnorm_k(const float* __restrict__ Yl,
                                                 float* __restrict__ rsc) {
    int b = blockIdx.y;
    int c = blockIdx.x * 256 + threadIdx.x;
    const float* base = Yl + (long long)b * DD * CC + c;
    float s = 0.0f;
    for (int d = 0; d < DD; ++d) { float v = base[(long long)d * CC]; s += v * v; }
    rsc[(long long)b * CC + c] = 1.0f / fmaxf(sqrtf(s), 1e-12f);
}

// ---------------------------------------------------------------------------
// transpose + column-scale + split: Yl[B][D][C] -> Ylt planes [B][C][D]
// ---------------------------------------------------------------------------
__global__ __launch_bounds__(256) void trans_split_k(const float* __restrict__ in,
                                                     const float* __restrict__ scale,
                                                     u16* __restrict__ hi, u16* __restrict__ lo) {
    __shared__ float tile[32][33];
    int s0 = blockIdx.x * 32, r0 = blockIdx.y * 32, b = blockIdx.z;
    const float* inb = in + (long long)b * DD * CC;
    int tx = threadIdx.x & 31, ty = threadIdx.x >> 5;
    for (int i = ty; i < 32; i += 8)
        tile[i][tx] = inb[(long long)(r0 + i) * CC + s0 + tx];
    __syncthreads();
    for (int i = ty; i < 32; i += 8) {
        float v = tile[tx][i] * scale[(long long)b * CC + s0 + i];
        unsigned short hh, ll; split2(v, hh, ll);
        long long o = (long long)b * DD * CC + (long long)(s0 + i) * DD + r0 + tx;
        hi[o] = hh; lo[o] = ll;
    }
}

// ---------------------------------------------------------------------------
// Sum 4 K-split parts of latent [B][D][HW] -> split planes + transposed planes
// ---------------------------------------------------------------------------
__global__ __launch_bounds__(256) void latreduce_k(const float* __restrict__ parts,
                                                   u16* __restrict__ hi, u16* __restrict__ lo,
                                                   u16* __restrict__ thi, u16* __restrict__ tlo) {
    __shared__ float tile[32][33];
    int h0 = blockIdx.x * 32, d0 = blockIdx.y * 32, b = blockIdx.z;
    const long long sL = (long long)DD * HWW;
    const long long ps = (long long)BB * sL;
    const float* base = parts + (long long)b * sL;
    int tx = threadIdx.x & 31, ty = threadIdx.x >> 5;
    for (int i = ty; i < 32; i += 8) {
        long long o = (long long)(d0 + i) * HWW + h0 + tx;
        float s = base[o] + base[o + ps] + base[o + 2 * ps] + base[o + 3 * ps];
        tile[i][tx] = s;
        unsigned short hh, ll; split2(s, hh, ll);
        long long od = (long long)b * sL + o;
        hi[od] = hh; lo[od] = ll;
    }
    __syncthreads();
    for (int i = ty; i < 32; i += 8) {
        float v = tile[tx][i];
        unsigned short hh, ll; split2(v, hh, ll);
        long long ot = (long long)b * sL + (long long)(h0 + i) * DD + d0 + tx;
        thi[ot] = hh; tlo[ot] = ll;
    }
}

// ---------------------------------------------------------------------------
__global__ __launch_bounds__(256) void latnorm_k(const float* __restrict__ G,
                                                 float* __restrict__ rs) {
    int i = blockIdx.x * 256 + threadIdx.x;
    int b = i >> 8, d = i & 255;
    float v = G[((long long)b * DD + d) * DD + d];
    rs[i] = 1.0f / fmaxf(sqrtf(v), 1e-12f);
}

// softmax over gram rows -> aff hi/lo planes
__global__ __launch_bounds__(256) void softmax_k(const float* __restrict__ G,
                                                 const float* __restrict__ rs,
                                                 u16* __restrict__ affHi,
                                                 u16* __restrict__ affLo) {
    int d = blockIdx.x, b = blockIdx.y;
    const float* row = G + ((long long)b * DD + d) * DD;
    const float* rsb = rs + (long long)b * DD;
    int t = threadIdx.x;
    float lg = row[t] * rsb[d] * rsb[t];

    float m = lg;
    for (int off = 32; off > 0; off >>= 1) m = fmaxf(m, __shfl_down(m, off, 64));
    __shared__ float wsm[4];
    __shared__ float bm, bs;
    int lane = t & 63, w = t >> 6;
    if (lane == 0) wsm[w] = m;
    __syncthreads();
    if (t == 0) bm = fmaxf(fmaxf(wsm[0], wsm[1]), fmaxf(wsm[2], wsm[3]));
    __syncthreads();
    float e = expf(lg - bm);
    float s = e;
    for (int off = 32; off > 0; off >>= 1) s += __shfl_down(s, off, 64);
    if (lane == 0) wsm[w] = s;
    __syncthreads();
    if (t == 0) bs = wsm[0] + wsm[1] + wsm[2] + wsm[3];
    __syncthreads();
    float v = e / bs;
    unsigned short hh, ll; split2(v, hh, ll);
    long long o = ((long long)b * DD + d) * DD + t;
    affHi[o] = hh; affLo[o] = ll;
}

// ---------------------------------------------------------------------------
extern "C" void kernel_launch(void* const* d_in, const int* in_sizes, int n_in,
                              void* d_out, int out_size, void* d_ws, size_t ws_size,
                              hipStream_t stream) {
    const float* v2l   = (const float*)d_in[0];
    const float* l2v   = (const float*)d_in[1];
    const float* w_v2l = (const float*)d_in[2];
    const float* g_v2l = (const float*)d_in[3];
    const float* b_v2l = (const float*)d_in[4];
    const float* w_l2v = (const float*)d_in[5];
    const float* g_l2v = (const float*)d_in[6];
    const float* b_l2v = (const float*)d_in[7];
    float* out = (float*)d_out;

    char* W = (char*)d_ws;
    float* Yv     = (float*)(W + 0);            // 32MB fp32 -> in-place permuted planes
    float* Yl     = (float*)(W + 33554432);     // 32MB
    u16*   YltHi  = (u16*)(W + 67108864);       // 16MB
    u16*   YltLo  = (u16*)(W + 83886080);       // 16MB
    u16*   latHi  = (u16*)(W + 100663296);      //  8MB
    u16*   latLo  = (u16*)(W + 109051904);      //  8MB
    u16*   latTHi = (u16*)(W + 117440512);      //  8MB
    u16*   latTLo = (u16*)(W + 125829120);      //  8MB
    u16*   l2tHi  = (u16*)(W + 134217728);      //  8MB
    u16*   l2tLo  = (u16*)(W + 142606336);      //  8MB
    float* gram   = (float*)(W + 150994944);    //  4MB
    float* rs     = (float*)(W + 155189248);
    float* rsc    = (float*)(W + 155205632);
    u16*   affHi  = (u16*)(W + 155336704);      //  2MB
    u16*   affLo  = (u16*)(W + 157433856);      //  2MB
    u16*   WvHi   = (u16*)(W + 159531008);      //  512KB each
    u16*   WvLo   = WvHi + 262144;
    u16*   WlHi   = WvLo + 262144;
    u16*   WlLo   = WlHi + 262144;

    // K-split latent parts (4 x [B][D][HW] fp32 = 64MB) live in d_out scratch
    float* latPart = (float*)d_out;

    const long long sY   = (long long)DD * CC;     // 524288
    const long long sL   = (long long)DD * HWW;    // 262144
    const long long sG   = (long long)DD * DD;     // 65536
    const long long sX   = (long long)CC * HWW;    // 2097152
    const long long sYp  = (long long)DD * 4096;   // in-place plane stride (u16)

    // weights -> planes
    split_k<<<128, 256, 0, stream>>>(w_v2l, WvHi, WvLo, 32768);
    split_k<<<128, 256, 0, stream>>>(w_l2v, WlHi, WlLo, 32768);

    // G1+G2 fused: Yv/Yl = relu(sc*(W . X^T)+b)  [D=256 x C=2048], K=1024
    gemm8<0, 1, 1, 1><<<dim3(CC / 256, 1, 32), 512, 0, stream>>>(
        WvHi, WvLo, WlHi, WlLo, 0, HWW,
        v2l, nullptr, l2v, nullptr, sX, HWW,
        Yv, Yl, sY, 0, CC, HWW,
        g_v2l, b_v2l, g_l2v, b_l2v);

    rownorm_split_perm_k<<<dim3(DD, BB), 256, 0, stream>>>(Yv);
    colnorm_k<<<dim3(CC / 256, BB), 256, 0, stream>>>(Yl, rsc);
    trans_split_k<<<dim3(CC / 32, DD / 32, BB), 256, 0, stream>>>(Yl, rsc, YltHi, YltLo);

    // G3 (K-split x4): latent parts = Yvn(k') . B'(k')^T  [D=256 x HW=1024]
    // per-part constant parity -> plain NT with shifted B base (done in-kernel)
    gemm8<0, 0, 0, 4><<<dim3(HWW / 256, 1, 64), 512, 0, stream>>>(
        (const u16*)Yv, (const u16*)Yv + 2048, nullptr, nullptr, sYp, 4096,
        v2l, nullptr, nullptr, nullptr, sX, HWW,
        latPart, nullptr, sL, (long long)BB * sL, HWW, 512,
        nullptr, nullptr, nullptr, nullptr);

    latreduce_k<<<dim3(HWW / 32, DD / 32, BB), 256, 0, stream>>>(
        latPart, latHi, latLo, latTHi, latTLo);

    // gram = latent . latent^T  (plane MFMA, fp32 out)
    mfma_gemm<64, 0><<<dim3(4, 2, BB), 256, 0, stream>>>(
        latHi, latLo, sL, HWW, latHi, latLo, sL, HWW,
        gram, nullptr, sG, DD, HWW);

    latnorm_k<<<dim3(BB * DD / 256), 256, 0, stream>>>(gram, rs);
    softmax_k<<<dim3(DD, BB), 256, 0, stream>>>(gram, rs, affHi, affLo);

    // lat2t = latentT . aff^T  [HW,D] -> planes
    mfma_gemm<128, 2><<<dim3(2, 8, BB), 256, 0, stream>>>(
        latTHi, latTLo, sL, DD, affHi, affLo, sG, DD,
        l2tHi, l2tLo, sL, DD, DD);

    // G6: out = Ylt . l2t^T  [C=2048 x HW=1024], K=256, both operands planes
    gemm8<1, 0, 0, 1><<<dim3(HWW / 256, CC / 256, BB), 512, 0, stream>>>(
        YltHi, YltLo, nullptr, nullptr, sY, DD,
        l2tHi, l2tLo, nullptr, nullptr, sL, DD,
        out, nullptr, sX, 0, HWW, DD,
        nullptr, nullptr, nullptr, nullptr);
}

// Round 8
// 364.849 us; speedup vs baseline: 1.1786x; 1.0437x over previous
//
#include <hip/hip_runtime.h>
#include <hip/hip_bf16.h>

#define BB 16
#define CC 2048
#define HWW 1024
#define DD 256
#define BN_RSQRT 0.9999950000374997f

typedef short bf16x8 __attribute__((ext_vector_type(8)));
typedef float f32x4 __attribute__((ext_vector_type(4)));
typedef unsigned short u16x8 __attribute__((ext_vector_type(8)));
typedef unsigned short u16x4 __attribute__((ext_vector_type(4)));
typedef unsigned short u16;

typedef __attribute__((address_space(1))) const unsigned GU;
typedef __attribute__((address_space(3))) unsigned LU;
__device__ __forceinline__ void gload16(const void* g, void* l) {
    __builtin_amdgcn_global_load_lds((GU*)g, (LU*)l, 16, 0, 0);
}

// ---- bf16 split helpers ----
__device__ __forceinline__ unsigned short f2bf(float x) {
    unsigned u = __builtin_bit_cast(unsigned, x);
    unsigned r = u + 0x7FFFu + ((u >> 16) & 1u);
    return (unsigned short)(r >> 16);
}
__device__ __forceinline__ float bf2f(unsigned short h) {
    unsigned u = ((unsigned)h) << 16;
    return __builtin_bit_cast(float, u);
}
__device__ __forceinline__ void split2(float x, unsigned short& hi, unsigned short& lo) {
    hi = f2bf(x);
    lo = f2bf(x - bf2f(hi));
}
// frag-read variant: RNE hi, truncated lo
__device__ __forceinline__ void split2t(float x, unsigned short& hi, unsigned short& lo) {
    hi = f2bf(x);
    float d = x - bf2f(hi);
    lo = (unsigned short)(__builtin_bit_cast(unsigned, d) >> 16);
}

struct RegsA { u16x8 h[2]; u16x8 l[2]; };
struct RegsB { u16x8 h[2]; u16x8 l[2]; };

// ---------------------------------------------------------------------------
// split fp32 -> hi/lo bf16 planes (weights only)
// ---------------------------------------------------------------------------
__global__ __launch_bounds__(256) void split_k(const float* __restrict__ in,
                                               u16* __restrict__ hi, u16* __restrict__ lo,
                                               long long n8) {
    long long i = (long long)blockIdx.x * 256 + threadIdx.x;
    if (i >= n8) return;
    const float4* p = (const float4*)in + i * 2;
    float4 a = p[0], b = p[1];
    float xs[8] = {a.x, a.y, a.z, a.w, b.x, b.y, b.z, b.w};
    u16x8 h, l;
    #pragma unroll
    for (int j = 0; j < 8; ++j) { unsigned short hh, ll; split2(xs[j], hh, ll); h[j] = hh; l[j] = ll; }
    *(u16x8*)(hi + i * 8) = h;
    *(u16x8*)(lo + i * 8) = l;
}

// ---------------------------------------------------------------------------
// gemm2b — 128x128-tile split-bf16 MFMA GEMM (NT), 8 waves, all-gload-lds,
// dbuf 2x32KB LDS (2 blocks/CU co-resident: the other block's MFMA hides this
// block's stage/barrier). Per wave: 64x32 out, 24 MFMA + 12 ds_read per tile.
// A: bf16 hi/lo planes (global). BF: 0 = B fp32 rows (split at frag read),
// 1 = B bf16 planes. EPI: 0 fp32 store, 1 relu(g*sc*x+b).
// FUSE2: grid.z=32, op=z>>4.  KS: K-split (z=16*KS), parity-safe base shift.
// ---------------------------------------------------------------------------
template <int BF, int EPI, int FUSE2, int KS>
__global__ __launch_bounds__(512, 4) void gemm2b(
    const u16* __restrict__ Ah0, const u16* __restrict__ Al0,
    const u16* __restrict__ Ah1, const u16* __restrict__ Al1,
    long long aB, int lda,
    const void* __restrict__ B0a, const void* __restrict__ B0b,
    const void* __restrict__ B1a, const void* __restrict__ B1b,
    long long bB, int ldb,
    float* __restrict__ C0, float* __restrict__ C1,
    long long cB, long long kB, int ldc,
    int K,
    const float* __restrict__ g0, const float* __restrict__ bb0,
    const float* __restrict__ g1, const float* __restrict__ bb1)
{
    __shared__ __attribute__((aligned(16))) char smem[2][32768];

    // bijective XCD-chunk swizzle (nwg % 8 == 0 for all grids used)
    const int gx = gridDim.x, gy = gridDim.y;
    int nwg = gx * gy * gridDim.z;
    int id = blockIdx.x + gx * (blockIdx.y + gy * blockIdx.z);
    int chunk = nwg >> 3;
    int nid = (id & 7) * chunk + (id >> 3);
    int bx = nid % gx;
    int tmp = nid / gx;
    int by = tmp % gy;
    int bz = tmp / gy;

    const int t = threadIdx.x;
    const int n0 = bx * 128, m0 = by * 128;

    int op = 0, batch, kz = 0;
    if constexpr (FUSE2) { op = bz >> 4; batch = bz & 15; }
    else if constexpr (KS > 1) { batch = bz / KS; kz = bz - batch * KS; }
    else { batch = bz; }
    const int koffA = kz * K;

    const u16* Ahp = (op ? Ah1 : Ah0) + (long long)batch * aB + koffA;
    const u16* Alp = (op ? Al1 : Al0) + (long long)batch * aB + koffA;
    const float* Bf = nullptr;
    const u16* Bh = nullptr;
    const u16* Bl = nullptr;
    if constexpr (BF == 0) {
        Bf = (const float*)(op ? B1a : B0a) + (long long)batch * bB;
        // k'-parity base shift (G3); zero when koffA==0
        Bf += ((long long)(koffA >> 10)) * 1024 * ldb + (koffA & 1023);
    } else {
        Bh = (const u16*)(op ? B1a : B0a) + (long long)batch * bB;
        Bl = (const u16*)(op ? B1b : B0b) + (long long)batch * bB;
    }
    float* Cb = ((EPI == 1 && FUSE2) ? (op ? C1 : C0) : C0)
              + (long long)batch * cB + (long long)kz * kB;
    const float* gp = op ? g1 : g0;
    const float* bp = op ? bb1 : bb0;

    // ---- gload staging coords (inverse-swizzled SOURCE, linear LDS dest) ----
    const int arow = t >> 2;                          // A rows 0..127
    const int aslt = (t & 3) ^ ((t >> 3) & 3);        // A source 16B slot
    const int brow = t >> 3;                          // B fp32 rows 0..63 (+64)
    const int bslt = (t & 7) ^ ((t >> 3) & 7);        // B source 16B slot

    // ---- fragment coords: 8 waves -> wr in {0,1}, wc in {0..3} ----
    const int l = t & 63, w = t >> 6;
    const int wr = w >> 2, wc = w & 3;
    const int rl = l & 15, kq = l >> 4;
    const int fsw = (kq ^ ((rl >> 1) & 3)) * 16;

    f32x4 acc[4][2];
    #pragma unroll
    for (int i = 0; i < 4; ++i)
        #pragma unroll
        for (int j = 0; j < 2; ++j)
            acc[i][j] = (f32x4){0.f, 0.f, 0.f, 0.f};

    auto gstage = [&](int k0, char* sn) {
        const u16* pa = Ahp + (long long)(m0 + arow) * lda + k0 + aslt * 8;
        gload16(pa, sn + t * 16);
        const u16* pl = Alp + (long long)(m0 + arow) * lda + k0 + aslt * 8;
        gload16(pl, sn + 8192 + t * 16);
        if constexpr (BF == 0) {
            const float* pb = Bf + (long long)(n0 + brow) * ldb + k0 + bslt * 4;
            gload16(pb,                       sn + 16384 + t * 16);
            gload16(pb + (long long)64 * ldb, sn + 24576 + t * 16);
        } else {
            const u16* pbh = Bh + (long long)(n0 + arow) * ldb + k0 + aslt * 8;
            gload16(pbh, sn + 16384 + t * 16);
            const u16* pbl = Bl + (long long)(n0 + arow) * ldb + k0 + aslt * 8;
            gload16(pbl, sn + 24576 + t * 16);
        }
    };

    auto readA = [&](const char* sb, bf16x8* fah, bf16x8* fal) {
        #pragma unroll
        for (int i2 = 0; i2 < 4; ++i2) {
            int off = (wr * 64 + i2 * 16 + rl) * 64 + fsw;
            fah[i2] = *(const bf16x8*)(sb + off);
            fal[i2] = *(const bf16x8*)(sb + 8192 + off);
        }
    };
    auto readB = [&](const char* sb, bf16x8* fbh, bf16x8* fbl) {
        #pragma unroll
        for (int j = 0; j < 2; ++j) {
            int row = wc * 32 + j * 16 + rl;
            if constexpr (BF == 0) {
                const char* p = sb + 16384 + row * 128;
                int g = rl & 7;
                float4 x0 = *(const float4*)(p + ((2 * kq) ^ g) * 16);
                float4 x1 = *(const float4*)(p + ((2 * kq + 1) ^ g) * 16);
                float xs[8] = {x0.x, x0.y, x0.z, x0.w, x1.x, x1.y, x1.z, x1.w};
                u16x8 h, lo;
                #pragma unroll
                for (int e = 0; e < 8; ++e) {
                    unsigned short hh, ll; split2t(xs[e], hh, ll);
                    h[e] = hh; lo[e] = ll;
                }
                fbh[j] = __builtin_bit_cast(bf16x8, h);
                fbl[j] = __builtin_bit_cast(bf16x8, lo);
            } else {
                int off = row * 64 + fsw;
                fbh[j] = *(const bf16x8*)(sb + 16384 + off);
                fbl[j] = *(const bf16x8*)(sb + 24576 + off);
            }
        }
    };

    const int NIT = K >> 5;

    gstage(0, smem[0]);
    asm volatile("s_waitcnt vmcnt(0)" ::: "memory");
    __builtin_amdgcn_s_barrier();

    for (int it = 0; it < NIT; ++it) {
        char* sb = smem[it & 1];
        char* sn = smem[(it + 1) & 1];
        const bool more = (it + 1) < NIT;
        if (more) gstage((it + 1) << 5, sn);

        bf16x8 fah[4], fal[4], fbh[2], fbl[2];
        readB(sb, fbh, fbl);
        readA(sb, fah, fal);

        __builtin_amdgcn_s_setprio(1);
        #pragma unroll
        for (int i2 = 0; i2 < 4; ++i2)
            #pragma unroll
            for (int j = 0; j < 2; ++j)
                acc[i2][j] = __builtin_amdgcn_mfma_f32_16x16x32_bf16(fal[i2], fbh[j], acc[i2][j], 0, 0, 0);
        #pragma unroll
        for (int i2 = 0; i2 < 4; ++i2)
            #pragma unroll
            for (int j = 0; j < 2; ++j)
                acc[i2][j] = __builtin_amdgcn_mfma_f32_16x16x32_bf16(fah[i2], fbl[j], acc[i2][j], 0, 0, 0);
        #pragma unroll
        for (int i2 = 0; i2 < 4; ++i2)
            #pragma unroll
            for (int j = 0; j < 2; ++j)
                acc[i2][j] = __builtin_amdgcn_mfma_f32_16x16x32_bf16(fah[i2], fbh[j], acc[i2][j], 0, 0, 0);
        __builtin_amdgcn_s_setprio(0);

        if (more) { asm volatile("s_waitcnt vmcnt(0)" ::: "memory"); }
        __builtin_amdgcn_s_barrier();
    }

    // ---- epilogue ----
    #pragma unroll
    for (int i = 0; i < 4; ++i) {
        #pragma unroll
        for (int r = 0; r < 4; ++r) {
            int row = m0 + wr * 64 + i * 16 + kq * 4 + r;
            float sc = 1.0f, bi = 0.0f;
            if (EPI == 1) { sc = gp[row] * BN_RSQRT; bi = bp[row]; }
            #pragma unroll
            for (int j = 0; j < 2; ++j) {
                int col = n0 + wc * 32 + j * 16 + rl;
                float v = acc[i][j][r];
                if (EPI == 1) v = fmaxf(fmaf(v, sc, bi), 0.0f);
                Cb[(long long)row * ldc + col] = v;
            }
        }
    }
}

// ---------------------------------------------------------------------------
// 128-wide split-bf16 MFMA GEMM (gram + lat2t), plane inputs only
// ---------------------------------------------------------------------------
template <int BN_, int EPI>
__global__ __launch_bounds__(256) void mfma_gemm(
    const void* __restrict__ Ap, const void* __restrict__ Ap2, long long aB, int lda,
    const void* __restrict__ Bp, const void* __restrict__ Bp2, long long bB, int ldb,
    void* __restrict__ Cp, void* __restrict__ Cp2,
    long long cB, int ldc, int K)
{
    constexpr int NJ   = BN_ / 32;
    constexpr int BNB  = BN_ * 64;
    constexpr int BUFB = 16384 + BN_ * 128;
    __shared__ __attribute__((aligned(16))) char smem[2][BUFB];

    const int gx = gridDim.x, gy = gridDim.y;
    int nwg = gx * gy * gridDim.z;
    int id = blockIdx.x + gx * (blockIdx.y + gy * blockIdx.z);
    int chunk = nwg >> 3;
    int nid = (id & 7) * chunk + (id >> 3);
    int bx = nid % gx;
    int tmp = nid / gx;
    int by = tmp % gy;
    int bz = tmp / gy;

    const int t  = threadIdx.x;
    const int n0 = bx * BN_;
    const int m0 = by * 128;

    const int ar = t >> 1, ag = t & 1;
    const int af = (ar >> 1) & 3;
    const int as0 = (2 * ag) ^ af, as1 = (2 * ag + 1) ^ af;
    const bool bact = (BN_ == 128) || (t < 2 * BN_);
    const int br = (t >> 1) & (BN_ - 1), bg = t & 1;
    const int bf = (br >> 1) & 3;
    const int bs0 = (2 * bg) ^ bf, bs1 = (2 * bg + 1) ^ bf;

    const int l  = t & 63, w = t >> 6;
    const int wr = w >> 1, wc = w & 1;
    const int rl = l & 15, kq = l >> 4;
    const int sw = kq ^ ((rl >> 1) & 3);
    const int aoff = (wr * 64 + rl) * 64 + sw * 16;
    const int boff = (wc * (BN_ / 2) + rl) * 64 + sw * 16;

    const u16* Ahp = (const u16*)Ap  + (long long)bz * aB;
    const u16* Alp = (const u16*)Ap2 + (long long)bz * aB;
    const u16* Bhp = (const u16*)Bp  + (long long)bz * bB;
    const u16* Blp = (const u16*)Bp2 + (long long)bz * bB;

    auto loadA = [&](int k0, RegsA& ra) {
        const u16* ph = Ahp + (long long)(m0 + ar) * lda + k0 + ag * 16;
        const u16* pl = Alp + (long long)(m0 + ar) * lda + k0 + ag * 16;
        ra.h[0] = *(const u16x8*)(ph);
        ra.h[1] = *(const u16x8*)(ph + 8);
        ra.l[0] = *(const u16x8*)(pl);
        ra.l[1] = *(const u16x8*)(pl + 8);
    };
    auto loadB = [&](int k0, RegsB& rb) {
        if (!bact) return;
        const u16* ph = Bhp + (long long)(n0 + br) * ldb + k0 + bg * 16;
        const u16* pl = Blp + (long long)(n0 + br) * ldb + k0 + bg * 16;
        rb.h[0] = *(const u16x8*)(ph);
        rb.h[1] = *(const u16x8*)(ph + 8);
        rb.l[0] = *(const u16x8*)(pl);
        rb.l[1] = *(const u16x8*)(pl + 8);
    };
    auto stageWrite = [&](char* sb, RegsA& ra, RegsB& rb) {
        *(u16x8*)(sb + ar * 64 + as0 * 16) = ra.h[0];
        *(u16x8*)(sb + ar * 64 + as1 * 16) = ra.h[1];
        *(u16x8*)(sb + 8192 + ar * 64 + as0 * 16) = ra.l[0];
        *(u16x8*)(sb + 8192 + ar * 64 + as1 * 16) = ra.l[1];
        if (bact) {
            char* sB = sb + 16384;
            *(u16x8*)(sB + br * 64 + bs0 * 16) = rb.h[0];
            *(u16x8*)(sB + br * 64 + bs1 * 16) = rb.h[1];
            *(u16x8*)(sB + BNB + br * 64 + bs0 * 16) = rb.l[0];
            *(u16x8*)(sB + BNB + br * 64 + bs1 * 16) = rb.l[1];
        }
    };

    f32x4 acc[4][NJ];
    #pragma unroll
    for (int i = 0; i < 4; ++i)
        #pragma unroll
        for (int j = 0; j < NJ; ++j)
            acc[i][j] = (f32x4){0.f, 0.f, 0.f, 0.f};

    RegsA a0, a1;
    RegsB b0, b1;
    const int NIT = K >> 5;

    loadA(0, a0); loadB(0, b0);
    stageWrite(smem[0], a0, b0);
    loadA(32, a1); loadB(32, b1);
    asm volatile("s_waitcnt lgkmcnt(0)" ::: "memory");
    __builtin_amdgcn_s_barrier();

    auto step = [&](int it, char* sb, char* sn, RegsA& pa, RegsB& pb,
                    RegsA& qa, RegsB& qb) {
        bf16x8 fah[4], fal[4], fbh[NJ], fbl[NJ];
        #pragma unroll
        for (int i = 0; i < 4; ++i) {
            fah[i] = *(const bf16x8*)(sb + aoff + i * 1024);
            fal[i] = *(const bf16x8*)(sb + 8192 + aoff + i * 1024);
        }
        #pragma unroll
        for (int j = 0; j < NJ; ++j) {
            fbh[j] = *(const bf16x8*)(sb + 16384 + boff + j * 1024);
            fbl[j] = *(const bf16x8*)(sb + 16384 + BNB + boff + j * 1024);
        }
        if (it + 1 < NIT) stageWrite(sn, pa, pb);
        if (it + 2 < NIT) { loadA((it + 2) << 5, qa); loadB((it + 2) << 5, qb); }
        #pragma unroll
        for (int i = 0; i < 4; ++i)
            #pragma unroll
            for (int j = 0; j < NJ; ++j) {
                acc[i][j] = __builtin_amdgcn_mfma_f32_16x16x32_bf16(fal[i], fbh[j], acc[i][j], 0, 0, 0);
                acc[i][j] = __builtin_amdgcn_mfma_f32_16x16x32_bf16(fah[i], fbl[j], acc[i][j], 0, 0, 0);
                acc[i][j] = __builtin_amdgcn_mfma_f32_16x16x32_bf16(fah[i], fbh[j], acc[i][j], 0, 0, 0);
            }
        asm volatile("s_waitcnt lgkmcnt(0)" ::: "memory");
        __builtin_amdgcn_s_barrier();
    };

    for (int it = 0; it < NIT; it += 2) {
        step(it,     smem[0], smem[1], a1, b1, a0, b0);
        step(it + 1, smem[1], smem[0], a0, b0, a1, b1);
    }

    #pragma unroll
    for (int i = 0; i < 4; ++i) {
        #pragma unroll
        for (int r = 0; r < 4; ++r) {
            int row = m0 + wr * 64 + i * 16 + kq * 4 + r;
            #pragma unroll
            for (int j = 0; j < NJ; ++j) {
                int col = n0 + wc * (BN_ / 2) + j * 16 + rl;
                float v = acc[i][j][r];
                if constexpr (EPI == 0) {
                    ((float*)Cp + (long long)bz * cB)[(long long)row * ldc + col] = v;
                } else {
                    unsigned short hh, ll; split2(v, hh, ll);
                    ((u16*)Cp  + (long long)bz * cB)[(long long)row * ldc + col] = hh;
                    ((u16*)Cp2 + (long long)bz * cB)[(long long)row * ldc + col] = ll;
                }
            }
        }
    }
}

// ---------------------------------------------------------------------------
// Row L2-norm over C of Y[B][D][C] fp32 -> in-place K'-PERMUTED split planes:
// row layout [hi 2048][lo 2048] (lda=4096), k' = (c&1)*1024 + (c>>1).
// ---------------------------------------------------------------------------
__global__ __launch_bounds__(256) void rownorm_split_perm_k(float* __restrict__ Y) {
    int d = blockIdx.x, b = blockIdx.y, t = threadIdx.x;
    float* row = Y + ((long long)b * DD + d) * CC;
    float4 v0 = ((const float4*)row)[2 * t];
    float4 v1 = ((const float4*)row)[2 * t + 1];
    float s = v0.x * v0.x + v0.y * v0.y + v0.z * v0.z + v0.w * v0.w
            + v1.x * v1.x + v1.y * v1.y + v1.z * v1.z + v1.w * v1.w;
    for (int off = 32; off > 0; off >>= 1) s += __shfl_down(s, off, 64);
    __shared__ float wsum[4];
    __shared__ float ivs;
    int lane = t & 63, w = t >> 6;
    if (lane == 0) wsum[w] = s;
    __syncthreads();
    if (t == 0) ivs = 1.0f / fmaxf(sqrtf(wsum[0] + wsum[1] + wsum[2] + wsum[3]), 1e-12f);
    __syncthreads();
    float iv = ivs;
    float xs[8] = {v0.x * iv, v0.y * iv, v0.z * iv, v0.w * iv,
                   v1.x * iv, v1.y * iv, v1.z * iv, v1.w * iv};
    u16x4 he, ho, le, lo4;
    #pragma unroll
    for (int j = 0; j < 4; ++j) {
        unsigned short hh, ll;
        split2(xs[2 * j], hh, ll);       he[j] = hh; le[j] = ll;
        split2(xs[2 * j + 1], hh, ll);   ho[j] = hh; lo4[j] = ll;
    }
    u16* hi = (u16*)row;
    *(u16x4*)(hi + 4 * t) = he;
    *(u16x4*)(hi + 1024 + 4 * t) = ho;
    *(u16x4*)(hi + 2048 + 4 * t) = le;
    *(u16x4*)(hi + 3072 + 4 * t) = lo4;
}

// ---------------------------------------------------------------------------
__global__ __launch_bounds__(256) void colnorm_k(const float* __restrict__ Yl,
                                                 float* __restrict__ rsc) {
    int b = blockIdx.y;
    int c = blockIdx.x * 256 + threadIdx.x;
    const float* base = Yl + (long long)b * DD * CC + c;
    float s = 0.0f;
    for (int d = 0; d < DD; ++d) { float v = base[(long long)d * CC]; s += v * v; }
    rsc[(long long)b * CC + c] = 1.0f / fmaxf(sqrtf(s), 1e-12f);
}

// ---------------------------------------------------------------------------
// transpose + column-scale + split: Yl[B][D][C] -> Ylt planes [B][C][D]
// ---------------------------------------------------------------------------
__global__ __launch_bounds__(256) void trans_split_k(const float* __restrict__ in,
                                                     const float* __restrict__ scale,
                                                     u16* __restrict__ hi, u16* __restrict__ lo) {
    __shared__ float tile[32][33];
    int s0 = blockIdx.x * 32, r0 = blockIdx.y * 32, b = blockIdx.z;
    const float* inb = in + (long long)b * DD * CC;
    int tx = threadIdx.x & 31, ty = threadIdx.x >> 5;
    for (int i = ty; i < 32; i += 8)
        tile[i][tx] = inb[(long long)(r0 + i) * CC + s0 + tx];
    __syncthreads();
    for (int i = ty; i < 32; i += 8) {
        float v = tile[tx][i] * scale[(long long)b * CC + s0 + i];
        unsigned short hh, ll; split2(v, hh, ll);
        long long o = (long long)b * DD * CC + (long long)(s0 + i) * DD + r0 + tx;
        hi[o] = hh; lo[o] = ll;
    }
}

// ---------------------------------------------------------------------------
// Sum 2 K-split parts of latent [B][D][HW] -> split planes + transposed planes
// ---------------------------------------------------------------------------
__global__ __launch_bounds__(256) void latreduce_k(const float* __restrict__ parts,
                                                   u16* __restrict__ hi, u16* __restrict__ lo,
                                                   u16* __restrict__ thi, u16* __restrict__ tlo) {
    __shared__ float tile[32][33];
    int h0 = blockIdx.x * 32, d0 = blockIdx.y * 32, b = blockIdx.z;
    const long long sL = (long long)DD * HWW;
    const long long ps = (long long)BB * sL;
    const float* base = parts + (long long)b * sL;
    int tx = threadIdx.x & 31, ty = threadIdx.x >> 5;
    for (int i = ty; i < 32; i += 8) {
        long long o = (long long)(d0 + i) * HWW + h0 + tx;
        float s = base[o] + base[o + ps];
        tile[i][tx] = s;
        unsigned short hh, ll; split2(s, hh, ll);
        long long od = (long long)b * sL + o;
        hi[od] = hh; lo[od] = ll;
    }
    __syncthreads();
    for (int i = ty; i < 32; i += 8) {
        float v = tile[tx][i];
        unsigned short hh, ll; split2(v, hh, ll);
        long long ot = (long long)b * sL + (long long)(h0 + i) * DD + d0 + tx;
        thi[ot] = hh; tlo[ot] = ll;
    }
}

// ---------------------------------------------------------------------------
__global__ __launch_bounds__(256) void latnorm_k(const float* __restrict__ G,
                                                 float* __restrict__ rs) {
    int i = blockIdx.x * 256 + threadIdx.x;
    int b = i >> 8, d = i & 255;
    float v = G[((long long)b * DD + d) * DD + d];
    rs[i] = 1.0f / fmaxf(sqrtf(v), 1e-12f);
}

// softmax over gram rows -> aff hi/lo planes
__global__ __launch_bounds__(256) void softmax_k(const float* __restrict__ G,
                                                 const float* __restrict__ rs,
                                                 u16* __restrict__ affHi,
                                                 u16* __restrict__ affLo) {
    int d = blockIdx.x, b = blockIdx.y;
    const float* row = G + ((long long)b * DD + d) * DD;
    const float* rsb = rs + (long long)b * DD;
    int t = threadIdx.x;
    float lg = row[t] * rsb[d] * rsb[t];

    float m = lg;
    for (int off = 32; off > 0; off >>= 1) m = fmaxf(m, __shfl_down(m, off, 64));
    __shared__ float wsm[4];
    __shared__ float bm, bs;
    int lane = t & 63, w = t >> 6;
    if (lane == 0) wsm[w] = m;
    __syncthreads();
    if (t == 0) bm = fmaxf(fmaxf(wsm[0], wsm[1]), fmaxf(wsm[2], wsm[3]));
    __syncthreads();
    float e = expf(lg - bm);
    float s = e;
    for (int off = 32; off > 0; off >>= 1) s += __shfl_down(s, off, 64);
    if (lane == 0) wsm[w] = s;
    __syncthreads();
    if (t == 0) bs = wsm[0] + wsm[1] + wsm[2] + wsm[3];
    __syncthreads();
    float v = e / bs;
    unsigned short hh, ll; split2(v, hh, ll);
    long long o = ((long long)b * DD + d) * DD + t;
    affHi[o] = hh; affLo[o] = ll;
}

// ---------------------------------------------------------------------------
extern "C" void kernel_launch(void* const* d_in, const int* in_sizes, int n_in,
                              void* d_out, int out_size, void* d_ws, size_t ws_size,
                              hipStream_t stream) {
    const float* v2l   = (const float*)d_in[0];
    const float* l2v   = (const float*)d_in[1];
    const float* w_v2l = (const float*)d_in[2];
    const float* g_v2l = (const float*)d_in[3];
    const float* b_v2l = (const float*)d_in[4];
    const float* w_l2v = (const float*)d_in[5];
    const float* g_l2v = (const float*)d_in[6];
    const float* b_l2v = (const float*)d_in[7];
    float* out = (float*)d_out;

    char* W = (char*)d_ws;
    float* Yv     = (float*)(W + 0);            // 32MB fp32 -> in-place permuted planes
    float* Yl     = (float*)(W + 33554432);     // 32MB
    u16*   YltHi  = (u16*)(W + 67108864);       // 16MB
    u16*   YltLo  = (u16*)(W + 83886080);       // 16MB
    u16*   latHi  = (u16*)(W + 100663296);      //  8MB
    u16*   latLo  = (u16*)(W + 109051904);      //  8MB
    u16*   latTHi = (u16*)(W + 117440512);      //  8MB
    u16*   latTLo = (u16*)(W + 125829120);      //  8MB
    u16*   l2tHi  = (u16*)(W + 134217728);      //  8MB
    u16*   l2tLo  = (u16*)(W + 142606336);      //  8MB
    float* gram   = (float*)(W + 150994944);    //  4MB
    float* rs     = (float*)(W + 155189248);
    float* rsc    = (float*)(W + 155205632);
    u16*   affHi  = (u16*)(W + 155336704);      //  2MB
    u16*   affLo  = (u16*)(W + 157433856);      //  2MB
    u16*   WvHi   = (u16*)(W + 159531008);      //  512KB each
    u16*   WvLo   = WvHi + 262144;
    u16*   WlHi   = WvLo + 262144;
    u16*   WlLo   = WlHi + 262144;

    // K-split latent parts (2 x [B][D][HW] fp32 = 32MB) live in d_out scratch
    float* latPart = (float*)d_out;

    const long long sY   = (long long)DD * CC;     // 524288
    const long long sL   = (long long)DD * HWW;    // 262144
    const long long sG   = (long long)DD * DD;     // 65536
    const long long sX   = (long long)CC * HWW;    // 2097152
    const long long sYp  = (long long)DD * 4096;   // in-place plane stride (u16)

    // weights -> planes
    split_k<<<128, 256, 0, stream>>>(w_v2l, WvHi, WvLo, 32768);
    split_k<<<128, 256, 0, stream>>>(w_l2v, WlHi, WlLo, 32768);

    // G1+G2 fused: Yv/Yl = relu(sc*(W . X^T)+b)  [D=256 x C=2048], K=1024
    // grid 16x2x32 = 1024 blocks -> 2 blocks/CU co-resident
    gemm2b<0, 1, 1, 1><<<dim3(CC / 128, DD / 128, 32), 512, 0, stream>>>(
        WvHi, WvLo, WlHi, WlLo, 0, HWW,
        v2l, nullptr, l2v, nullptr, sX, HWW,
        Yv, Yl, sY, 0, CC, HWW,
        g_v2l, b_v2l, g_l2v, b_l2v);

    rownorm_split_perm_k<<<dim3(DD, BB), 256, 0, stream>>>(Yv);
    colnorm_k<<<dim3(CC / 256, BB), 256, 0, stream>>>(Yl, rsc);
    trans_split_k<<<dim3(CC / 32, DD / 32, BB), 256, 0, stream>>>(Yl, rsc, YltHi, YltLo);

    // G3 (K-split x2, parity-aligned): latent parts = Yvn(k') . B'(k')^T
    // [D=256 x HW=1024], K=1024/part; grid 8x2x32 = 512 blocks
    gemm2b<0, 0, 0, 2><<<dim3(HWW / 128, DD / 128, 32), 512, 0, stream>>>(
        (const u16*)Yv, (const u16*)Yv + 2048, nullptr, nullptr, sYp, 4096,
        v2l, nullptr, nullptr, nullptr, sX, HWW,
        latPart, nullptr, sL, (long long)BB * sL, HWW, 1024,
        nullptr, nullptr, nullptr, nullptr);

    latreduce_k<<<dim3(HWW / 32, DD / 32, BB), 256, 0, stream>>>(
        latPart, latHi, latLo, latTHi, latTLo);

    // gram = latent . latent^T  (plane MFMA, fp32 out)
    mfma_gemm<64, 0><<<dim3(4, 2, BB), 256, 0, stream>>>(
        latHi, latLo, sL, HWW, latHi, latLo, sL, HWW,
        gram, nullptr, sG, DD, HWW);

    latnorm_k<<<dim3(BB * DD / 256), 256, 0, stream>>>(gram, rs);
    softmax_k<<<dim3(DD, BB), 256, 0, stream>>>(gram, rs, affHi, affLo);

    // lat2t = latentT . aff^T  [HW,D] -> planes
    mfma_gemm<128, 2><<<dim3(2, 8, BB), 256, 0, stream>>>(
        latTHi, latTLo, sL, DD, affHi, affLo, sG, DD,
        l2tHi, l2tLo, sL, DD, DD);

    // G6: out = Ylt . l2t^T  [C=2048 x HW=1024], K=256, both operands planes
    // grid 8x16x16 = 2048 blocks
    gemm2b<1, 0, 0, 1><<<dim3(HWW / 128, CC / 128, BB), 512, 0, stream>>>(
        YltHi, YltLo, nullptr, nullptr, sY, DD,
        l2tHi, l2tLo, nullptr, nullptr, sL, DD,
        out, nullptr, sX, 0, HWW, DD,
        nullptr, nullptr, nullptr, nullptr);
}

// Round 9
// 345.666 us; speedup vs baseline: 1.2440x; 1.0555x over previous
//
#include <hip/hip_runtime.h>
#include <hip/hip_bf16.h>

#define BB 16
#define CC 2048
#define HWW 1024
#define DD 256
#define BN_RSQRT 0.9999950000374997f

typedef short bf16x8 __attribute__((ext_vector_type(8)));
typedef float f32x4 __attribute__((ext_vector_type(4)));
typedef unsigned short u16x8 __attribute__((ext_vector_type(8)));
typedef unsigned short u16x4 __attribute__((ext_vector_type(4)));
typedef unsigned short u16;

typedef __attribute__((address_space(1))) const unsigned GU;
typedef __attribute__((address_space(3))) unsigned LU;
__device__ __forceinline__ void gload16(const void* g, void* l) {
    __builtin_amdgcn_global_load_lds((GU*)g, (LU*)l, 16, 0, 0);
}

// ---- bf16 split helpers (RNE) ----
__device__ __forceinline__ unsigned short f2bf(float x) {
    unsigned u = __builtin_bit_cast(unsigned, x);
    unsigned r = u + 0x7FFFu + ((u >> 16) & 1u);
    return (unsigned short)(r >> 16);
}
__device__ __forceinline__ float bf2f(unsigned short h) {
    unsigned u = ((unsigned)h) << 16;
    return __builtin_bit_cast(float, u);
}
__device__ __forceinline__ void split2(float x, unsigned short& hi, unsigned short& lo) {
    hi = f2bf(x);
    lo = f2bf(x - bf2f(hi));
}

struct RegsA { u16x8 h[2]; u16x8 l[2]; };
struct RegsB { u16x8 h[2]; u16x8 l[2]; };

// ---------------------------------------------------------------------------
// split fp32 -> hi/lo bf16 planes (weights only)
// ---------------------------------------------------------------------------
__global__ __launch_bounds__(256) void split_k(const float* __restrict__ in,
                                               u16* __restrict__ hi, u16* __restrict__ lo,
                                               long long n8) {
    long long i = (long long)blockIdx.x * 256 + threadIdx.x;
    if (i >= n8) return;
    const float4* p = (const float4*)in + i * 2;
    float4 a = p[0], b = p[1];
    float xs[8] = {a.x, a.y, a.z, a.w, b.x, b.y, b.z, b.w};
    u16x8 h, l;
    #pragma unroll
    for (int j = 0; j < 8; ++j) { unsigned short hh, ll; split2(xs[j], hh, ll); h[j] = hh; l[j] = ll; }
    *(u16x8*)(hi + i * 8) = h;
    *(u16x8*)(lo + i * 8) = l;
}

// ---------------------------------------------------------------------------
// gemm2b v2 — 128x128-tile split-bf16 MFMA GEMM (NT), 8 waves, dbuf 2x32KB,
// 2 blocks/CU. A: planes via global_load_lds. B:
//   BF=0: fp32 -> REGS (8/thread) -> split ONCE -> ds_write planes (swizzled)
//   BF=1: planes via global_load_lds
// Frag reads are plane-reads for both (zero VALU in frag path).
// vmcnt: B-regs issued before A-gloads -> mid vmcnt(2) = B only; end vmcnt(0).
// EPI: 0 fp32 store, 1 relu(g*sc*x+b). FUSE2: grid.z=32, op=z>>4. KS: K-split.
// ---------------------------------------------------------------------------
template <int BF, int EPI, int FUSE2, int KS>
__global__ __launch_bounds__(512, 4) void gemm2b(
    const u16* __restrict__ Ah0, const u16* __restrict__ Al0,
    const u16* __restrict__ Ah1, const u16* __restrict__ Al1,
    long long aB, int lda,
    const void* __restrict__ B0a, const void* __restrict__ B0b,
    const void* __restrict__ B1a, const void* __restrict__ B1b,
    long long bB, int ldb,
    float* __restrict__ C0, float* __restrict__ C1,
    long long cB, long long kB, int ldc,
    int K,
    const float* __restrict__ g0, const float* __restrict__ bb0,
    const float* __restrict__ g1, const float* __restrict__ bb1)
{
    __shared__ __attribute__((aligned(16))) char smem[2][32768];

    // bijective XCD-chunk swizzle (nwg % 8 == 0 for all grids used)
    const int gx = gridDim.x, gy = gridDim.y;
    int nwg = gx * gy * gridDim.z;
    int id = blockIdx.x + gx * (blockIdx.y + gy * blockIdx.z);
    int chunk = nwg >> 3;
    int nid = (id & 7) * chunk + (id >> 3);
    int bx = nid % gx;
    int tmp = nid / gx;
    int by = tmp % gy;
    int bz = tmp / gy;

    const int t = threadIdx.x;
    const int n0 = bx * 128, m0 = by * 128;

    int op = 0, batch, kz = 0;
    if constexpr (FUSE2) { op = bz >> 4; batch = bz & 15; }
    else if constexpr (KS > 1) { batch = bz / KS; kz = bz - batch * KS; }
    else { batch = bz; }
    const int koffA = kz * K;

    const u16* Ahp = (op ? Ah1 : Ah0) + (long long)batch * aB + koffA;
    const u16* Alp = (op ? Al1 : Al0) + (long long)batch * aB + koffA;
    const float* Bf = nullptr;
    const u16* Bh = nullptr;
    const u16* Bl = nullptr;
    if constexpr (BF == 0) {
        Bf = (const float*)(op ? B1a : B0a) + (long long)batch * bB;
        // k'-parity base shift (G3); zero when koffA==0
        Bf += ((long long)(koffA >> 10)) * 1024 * ldb + (koffA & 1023);
    } else {
        Bh = (const u16*)(op ? B1a : B0a) + (long long)batch * bB;
        Bl = (const u16*)(op ? B1b : B0b) + (long long)batch * bB;
    }
    float* Cb = ((EPI == 1 && FUSE2) ? (op ? C1 : C0) : C0)
              + (long long)batch * cB + (long long)kz * kB;
    const float* gp = op ? g1 : g0;
    const float* bp = op ? bb1 : bb0;

    // ---- staging coords ----
    const int arow = t >> 2;                          // rows 0..127
    const int aslt = (t & 3) ^ ((t >> 3) & 3);        // inverse-swz source slot
    const int bswz = (t & 3) ^ ((arow >> 1) & 3);     // B ds_write dest slot

    // ---- fragment coords: 8 waves -> wr in {0,1}, wc in {0..3} ----
    const int l = t & 63, w = t >> 6;
    const int wr = w >> 2, wc = w & 3;
    const int rl = l & 15, kq = l >> 4;
    const int fsw = (kq ^ ((rl >> 1) & 3)) * 16;

    f32x4 acc[4][2];
    #pragma unroll
    for (int i = 0; i < 4; ++i)
        #pragma unroll
        for (int j = 0; j < 2; ++j)
            acc[i][j] = (f32x4){0.f, 0.f, 0.f, 0.f};

    float4 rb0, rb1;   // B fp32 stage regs (BF==0)

    auto loadBregs = [&](int k0) {
        if constexpr (BF == 0) {
            const float* p = Bf + (long long)(n0 + arow) * ldb + k0 + (t & 3) * 8;
            rb0 = *(const float4*)p;
            rb1 = *(const float4*)(p + 4);
        }
    };
    auto gstage = [&](int k0, char* sn) {
        const u16* pa = Ahp + (long long)(m0 + arow) * lda + k0 + aslt * 8;
        gload16(pa, sn + t * 16);
        const u16* pl = Alp + (long long)(m0 + arow) * lda + k0 + aslt * 8;
        gload16(pl, sn + 8192 + t * 16);
        if constexpr (BF == 1) {
            const u16* pbh = Bh + (long long)(n0 + arow) * ldb + k0 + aslt * 8;
            gload16(pbh, sn + 16384 + t * 16);
            const u16* pbl = Bl + (long long)(n0 + arow) * ldb + k0 + aslt * 8;
            gload16(pbl, sn + 24576 + t * 16);
        }
    };
    auto splitWriteB = [&](char* sn) {
        if constexpr (BF == 0) {
            float xs[8] = {rb0.x, rb0.y, rb0.z, rb0.w, rb1.x, rb1.y, rb1.z, rb1.w};
            u16x8 h, lo;
            #pragma unroll
            for (int e = 0; e < 8; ++e) {
                unsigned short hh, ll; split2(xs[e], hh, ll);
                h[e] = hh; lo[e] = ll;
            }
            char* base = sn + 16384 + arow * 64 + bswz * 16;
            *(u16x8*)(base) = h;
            *(u16x8*)(base + 8192) = lo;
        }
    };

    auto readA = [&](const char* sb, bf16x8* fah, bf16x8* fal) {
        #pragma unroll
        for (int i2 = 0; i2 < 4; ++i2) {
            int off = (wr * 64 + i2 * 16 + rl) * 64 + fsw;
            fah[i2] = *(const bf16x8*)(sb + off);
            fal[i2] = *(const bf16x8*)(sb + 8192 + off);
        }
    };
    auto readB = [&](const char* sb, bf16x8* fbh, bf16x8* fbl) {
        #pragma unroll
        for (int j = 0; j < 2; ++j) {
            int off = (wc * 32 + j * 16 + rl) * 64 + fsw;
            fbh[j] = *(const bf16x8*)(sb + 16384 + off);
            fbl[j] = *(const bf16x8*)(sb + 24576 + off);
        }
    };

    const int NIT = K >> 5;

    // ---- prologue ----
    loadBregs(0);
    gstage(0, smem[0]);
    if constexpr (BF == 0) {
        asm volatile("s_waitcnt vmcnt(2)" ::: "memory");   // B regs ready
        splitWriteB(smem[0]);
    }
    asm volatile("s_waitcnt vmcnt(0)" ::: "memory");
    asm volatile("s_waitcnt lgkmcnt(0)" ::: "memory");
    __builtin_amdgcn_s_barrier();

    for (int it = 0; it < NIT; ++it) {
        char* sb = smem[it & 1];
        char* sn = smem[(it + 1) & 1];
        const bool more = (it + 1) < NIT;
        if (more) { loadBregs((it + 1) << 5); gstage((it + 1) << 5, sn); }

        bf16x8 fah[4], fal[4], fbh[2], fbl[2];
        readB(sb, fbh, fbl);
        readA(sb, fah, fal);

        if (more && BF == 0) {
            asm volatile("s_waitcnt vmcnt(2)" ::: "memory");   // B regs in
            splitWriteB(sn);
        }

        __builtin_amdgcn_s_setprio(1);
        #pragma unroll
        for (int i2 = 0; i2 < 4; ++i2)
            #pragma unroll
            for (int j = 0; j < 2; ++j)
                acc[i2][j] = __builtin_amdgcn_mfma_f32_16x16x32_bf16(fal[i2], fbh[j], acc[i2][j], 0, 0, 0);
        #pragma unroll
        for (int i2 = 0; i2 < 4; ++i2)
            #pragma unroll
            for (int j = 0; j < 2; ++j)
                acc[i2][j] = __builtin_amdgcn_mfma_f32_16x16x32_bf16(fah[i2], fbl[j], acc[i2][j], 0, 0, 0);
        #pragma unroll
        for (int i2 = 0; i2 < 4; ++i2)
            #pragma unroll
            for (int j = 0; j < 2; ++j)
                acc[i2][j] = __builtin_amdgcn_mfma_f32_16x16x32_bf16(fah[i2], fbh[j], acc[i2][j], 0, 0, 0);
        __builtin_amdgcn_s_setprio(0);

        if (more) { asm volatile("s_waitcnt vmcnt(0)" ::: "memory"); }
        asm volatile("s_waitcnt lgkmcnt(0)" ::: "memory");
        __builtin_amdgcn_s_barrier();
    }

    // ---- epilogue ----
    #pragma unroll
    for (int i = 0; i < 4; ++i) {
        #pragma unroll
        for (int r = 0; r < 4; ++r) {
            int row = m0 + wr * 64 + i * 16 + kq * 4 + r;
            float sc = 1.0f, bi = 0.0f;
            if (EPI == 1) { sc = gp[row] * BN_RSQRT; bi = bp[row]; }
            #pragma unroll
            for (int j = 0; j < 2; ++j) {
                int col = n0 + wc * 32 + j * 16 + rl;
                float v = acc[i][j][r];
                if (EPI == 1) v = fmaxf(fmaf(v, sc, bi), 0.0f);
                Cb[(long long)row * ldc + col] = v;
            }
        }
    }
}

// ---------------------------------------------------------------------------
// 128-wide split-bf16 MFMA GEMM (gram + lat2t), plane inputs only
// ---------------------------------------------------------------------------
template <int BN_, int EPI>
__global__ __launch_bounds__(256) void mfma_gemm(
    const void* __restrict__ Ap, const void* __restrict__ Ap2, long long aB, int lda,
    const void* __restrict__ Bp, const void* __restrict__ Bp2, long long bB, int ldb,
    void* __restrict__ Cp, void* __restrict__ Cp2,
    long long cB, int ldc, int K)
{
    constexpr int NJ   = BN_ / 32;
    constexpr int BNB  = BN_ * 64;
    constexpr int BUFB = 16384 + BN_ * 128;
    __shared__ __attribute__((aligned(16))) char smem[2][BUFB];

    const int gx = gridDim.x, gy = gridDim.y;
    int nwg = gx * gy * gridDim.z;
    int id = blockIdx.x + gx * (blockIdx.y + gy * blockIdx.z);
    int chunk = nwg >> 3;
    int nid = (id & 7) * chunk + (id >> 3);
    int bx = nid % gx;
    int tmp = nid / gx;
    int by = tmp % gy;
    int bz = tmp / gy;

    const int t  = threadIdx.x;
    const int n0 = bx * BN_;
    const int m0 = by * 128;

    const int ar = t >> 1, ag = t & 1;
    const int af = (ar >> 1) & 3;
    const int as0 = (2 * ag) ^ af, as1 = (2 * ag + 1) ^ af;
    const bool bact = (BN_ == 128) || (t < 2 * BN_);
    const int br = (t >> 1) & (BN_ - 1), bg = t & 1;
    const int bf = (br >> 1) & 3;
    const int bs0 = (2 * bg) ^ bf, bs1 = (2 * bg + 1) ^ bf;

    const int l  = t & 63, w = t >> 6;
    const int wr = w >> 1, wc = w & 1;
    const int rl = l & 15, kq = l >> 4;
    const int sw = kq ^ ((rl >> 1) & 3);
    const int aoff = (wr * 64 + rl) * 64 + sw * 16;
    const int boff = (wc * (BN_ / 2) + rl) * 64 + sw * 16;

    const u16* Ahp = (const u16*)Ap  + (long long)bz * aB;
    const u16* Alp = (const u16*)Ap2 + (long long)bz * aB;
    const u16* Bhp = (const u16*)Bp  + (long long)bz * bB;
    const u16* Blp = (const u16*)Bp2 + (long long)bz * bB;

    auto loadA = [&](int k0, RegsA& ra) {
        const u16* ph = Ahp + (long long)(m0 + ar) * lda + k0 + ag * 16;
        const u16* pl = Alp + (long long)(m0 + ar) * lda + k0 + ag * 16;
        ra.h[0] = *(const u16x8*)(ph);
        ra.h[1] = *(const u16x8*)(ph + 8);
        ra.l[0] = *(const u16x8*)(pl);
        ra.l[1] = *(const u16x8*)(pl + 8);
    };
    auto loadB = [&](int k0, RegsB& rb) {
        if (!bact) return;
        const u16* ph = Bhp + (long long)(n0 + br) * ldb + k0 + bg * 16;
        const u16* pl = Blp + (long long)(n0 + br) * ldb + k0 + bg * 16;
        rb.h[0] = *(const u16x8*)(ph);
        rb.h[1] = *(const u16x8*)(ph + 8);
        rb.l[0] = *(const u16x8*)(pl);
        rb.l[1] = *(const u16x8*)(pl + 8);
    };
    auto stageWrite = [&](char* sb, RegsA& ra, RegsB& rb) {
        *(u16x8*)(sb + ar * 64 + as0 * 16) = ra.h[0];
        *(u16x8*)(sb + ar * 64 + as1 * 16) = ra.h[1];
        *(u16x8*)(sb + 8192 + ar * 64 + as0 * 16) = ra.l[0];
        *(u16x8*)(sb + 8192 + ar * 64 + as1 * 16) = ra.l[1];
        if (bact) {
            char* sB = sb + 16384;
            *(u16x8*)(sB + br * 64 + bs0 * 16) = rb.h[0];
            *(u16x8*)(sB + br * 64 + bs1 * 16) = rb.h[1];
            *(u16x8*)(sB + BNB + br * 64 + bs0 * 16) = rb.l[0];
            *(u16x8*)(sB + BNB + br * 64 + bs1 * 16) = rb.l[1];
        }
    };

    f32x4 acc[4][NJ];
    #pragma unroll
    for (int i = 0; i < 4; ++i)
        #pragma unroll
        for (int j = 0; j < NJ; ++j)
            acc[i][j] = (f32x4){0.f, 0.f, 0.f, 0.f};

    RegsA a0, a1;
    RegsB b0, b1;
    const int NIT = K >> 5;

    loadA(0, a0); loadB(0, b0);
    stageWrite(smem[0], a0, b0);
    loadA(32, a1); loadB(32, b1);
    asm volatile("s_waitcnt lgkmcnt(0)" ::: "memory");
    __builtin_amdgcn_s_barrier();

    auto step = [&](int it, char* sb, char* sn, RegsA& pa, RegsB& pb,
                    RegsA& qa, RegsB& qb) {
        bf16x8 fah[4], fal[4], fbh[NJ], fbl[NJ];
        #pragma unroll
        for (int i = 0; i < 4; ++i) {
            fah[i] = *(const bf16x8*)(sb + aoff + i * 1024);
            fal[i] = *(const bf16x8*)(sb + 8192 + aoff + i * 1024);
        }
        #pragma unroll
        for (int j = 0; j < NJ; ++j) {
            fbh[j] = *(const bf16x8*)(sb + 16384 + boff + j * 1024);
            fbl[j] = *(const bf16x8*)(sb + 16384 + BNB + boff + j * 1024);
        }
        if (it + 1 < NIT) stageWrite(sn, pa, pb);
        if (it + 2 < NIT) { loadA((it + 2) << 5, qa); loadB((it + 2) << 5, qb); }
        #pragma unroll
        for (int i = 0; i < 4; ++i)
            #pragma unroll
            for (int j = 0; j < NJ; ++j) {
                acc[i][j] = __builtin_amdgcn_mfma_f32_16x16x32_bf16(fal[i], fbh[j], acc[i][j], 0, 0, 0);
                acc[i][j] = __builtin_amdgcn_mfma_f32_16x16x32_bf16(fah[i], fbl[j], acc[i][j], 0, 0, 0);
                acc[i][j] = __builtin_amdgcn_mfma_f32_16x16x32_bf16(fah[i], fbh[j], acc[i][j], 0, 0, 0);
            }
        asm volatile("s_waitcnt lgkmcnt(0)" ::: "memory");
        __builtin_amdgcn_s_barrier();
    };

    for (int it = 0; it < NIT; it += 2) {
        step(it,     smem[0], smem[1], a1, b1, a0, b0);
        step(it + 1, smem[1], smem[0], a0, b0, a1, b1);
    }

    #pragma unroll
    for (int i = 0; i < 4; ++i) {
        #pragma unroll
        for (int r = 0; r < 4; ++r) {
            int row = m0 + wr * 64 + i * 16 + kq * 4 + r;
            #pragma unroll
            for (int j = 0; j < NJ; ++j) {
                int col = n0 + wc * (BN_ / 2) + j * 16 + rl;
                float v = acc[i][j][r];
                if constexpr (EPI == 0) {
                    ((float*)Cp + (long long)bz * cB)[(long long)row * ldc + col] = v;
                } else {
                    unsigned short hh, ll; split2(v, hh, ll);
                    ((u16*)Cp  + (long long)bz * cB)[(long long)row * ldc + col] = hh;
                    ((u16*)Cp2 + (long long)bz * cB)[(long long)row * ldc + col] = ll;
                }
            }
        }
    }
}

// ---------------------------------------------------------------------------
// Row L2-norm over C of Y[B][D][C] fp32 -> in-place K'-PERMUTED split planes:
// row layout [hi 2048][lo 2048] (lda=4096), k' = (c&1)*1024 + (c>>1).
// ---------------------------------------------------------------------------
__global__ __launch_bounds__(256) void rownorm_split_perm_k(float* __restrict__ Y) {
    int d = blockIdx.x, b = blockIdx.y, t = threadIdx.x;
    float* row = Y + ((long long)b * DD + d) * CC;
    float4 v0 = ((const float4*)row)[2 * t];
    float4 v1 = ((const float4*)row)[2 * t + 1];
    float s = v0.x * v0.x + v0.y * v0.y + v0.z * v0.z + v0.w * v0.w
            + v1.x * v1.x + v1.y * v1.y + v1.z * v1.z + v1.w * v1.w;
    for (int off = 32; off > 0; off >>= 1) s += __shfl_down(s, off, 64);
    __shared__ float wsum[4];
    __shared__ float ivs;
    int lane = t & 63, w = t >> 6;
    if (lane == 0) wsum[w] = s;
    __syncthreads();
    if (t == 0) ivs = 1.0f / fmaxf(sqrtf(wsum[0] + wsum[1] + wsum[2] + wsum[3]), 1e-12f);
    __syncthreads();
    float iv = ivs;
    float xs[8] = {v0.x * iv, v0.y * iv, v0.z * iv, v0.w * iv,
                   v1.x * iv, v1.y * iv, v1.z * iv, v1.w * iv};
    u16x4 he, ho, le, lo4;
    #pragma unroll
    for (int j = 0; j < 4; ++j) {
        unsigned short hh, ll;
        split2(xs[2 * j], hh, ll);       he[j] = hh; le[j] = ll;
        split2(xs[2 * j + 1], hh, ll);   ho[j] = hh; lo4[j] = ll;
    }
    u16* hi = (u16*)row;
    *(u16x4*)(hi + 4 * t) = he;
    *(u16x4*)(hi + 1024 + 4 * t) = ho;
    *(u16x4*)(hi + 2048 + 4 * t) = le;
    *(u16x4*)(hi + 3072 + 4 * t) = lo4;
}

// ---------------------------------------------------------------------------
// FUSED column-norm + transpose + split:
// Yl[B][D=256][C] -> Ylt planes [B][C][D] scaled by 1/||col||_D.
// One block handles 32 c's x all 256 d's.
// ---------------------------------------------------------------------------
__global__ __launch_bounds__(256) void transnorm_k(const float* __restrict__ Yl,
                                                   u16* __restrict__ hi, u16* __restrict__ lo) {
    __shared__ float tile[256][33];
    __shared__ float part[8][33];
    __shared__ float invn[32];
    int c0 = blockIdx.x * 32, b = blockIdx.y;
    int t = threadIdx.x;
    int tx = t & 31, ty = t >> 5;
    const float* base = Yl + (long long)b * DD * CC + c0;
    for (int d = ty; d < 256; d += 8)
        tile[d][tx] = base[(long long)d * CC + tx];
    __syncthreads();
    float s = 0.0f;
    #pragma unroll
    for (int dd = 0; dd < 32; ++dd) {
        float v = tile[ty * 32 + dd][tx];
        s += v * v;
    }
    part[ty][tx] = s;
    __syncthreads();
    if (ty == 0) {
        float tot = part[0][tx] + part[1][tx] + part[2][tx] + part[3][tx]
                  + part[4][tx] + part[5][tx] + part[6][tx] + part[7][tx];
        invn[tx] = 1.0f / fmaxf(sqrtf(tot), 1e-12f);
    }
    __syncthreads();
    long long ob = (long long)b * DD * CC;
    #pragma unroll 4
    for (int i = 0; i < 32; ++i) {
        float v = tile[t][i] * invn[i];
        unsigned short hh, ll; split2(v, hh, ll);
        long long o = ob + (long long)(c0 + i) * DD + t;
        hi[o] = hh; lo[o] = ll;
    }
}

// ---------------------------------------------------------------------------
// Sum 2 K-split parts of latent [B][D][HW] -> split planes + transposed planes
// ---------------------------------------------------------------------------
__global__ __launch_bounds__(256) void latreduce_k(const float* __restrict__ parts,
                                                   u16* __restrict__ hi, u16* __restrict__ lo,
                                                   u16* __restrict__ thi, u16* __restrict__ tlo) {
    __shared__ float tile[32][33];
    int h0 = blockIdx.x * 32, d0 = blockIdx.y * 32, b = blockIdx.z;
    const long long sL = (long long)DD * HWW;
    const long long ps = (long long)BB * sL;
    const float* base = parts + (long long)b * sL;
    int tx = threadIdx.x & 31, ty = threadIdx.x >> 5;
    for (int i = ty; i < 32; i += 8) {
        long long o = (long long)(d0 + i) * HWW + h0 + tx;
        float s = base[o] + base[o + ps];
        tile[i][tx] = s;
        unsigned short hh, ll; split2(s, hh, ll);
        long long od = (long long)b * sL + o;
        hi[od] = hh; lo[od] = ll;
    }
    __syncthreads();
    for (int i = ty; i < 32; i += 8) {
        float v = tile[tx][i];
        unsigned short hh, ll; split2(v, hh, ll);
        long long ot = (long long)b * sL + (long long)(h0 + i) * DD + d0 + tx;
        thi[ot] = hh; tlo[ot] = ll;
    }
}

// ---------------------------------------------------------------------------
__global__ __launch_bounds__(256) void latnorm_k(const float* __restrict__ G,
                                                 float* __restrict__ rs) {
    int i = blockIdx.x * 256 + threadIdx.x;
    int b = i >> 8, d = i & 255;
    float v = G[((long long)b * DD + d) * DD + d];
    rs[i] = 1.0f / fmaxf(sqrtf(v), 1e-12f);
}

// softmax over gram rows -> aff hi/lo planes
__global__ __launch_bounds__(256) void softmax_k(const float* __restrict__ G,
                                                 const float* __restrict__ rs,
                                                 u16* __restrict__ affHi,
                                                 u16* __restrict__ affLo) {
    int d = blockIdx.x, b = blockIdx.y;
    const float* row = G + ((long long)b * DD + d) * DD;
    const float* rsb = rs + (long long)b * DD;
    int t = threadIdx.x;
    float lg = row[t] * rsb[d] * rsb[t];

    float m = lg;
    for (int off = 32; off > 0; off >>= 1) m = fmaxf(m, __shfl_down(m, off, 64));
    __shared__ float wsm[4];
    __shared__ float bm, bs;
    int lane = t & 63, w = t >> 6;
    if (lane == 0) wsm[w] = m;
    __syncthreads();
    if (t == 0) bm = fmaxf(fmaxf(wsm[0], wsm[1]), fmaxf(wsm[2], wsm[3]));
    __syncthreads();
    float e = expf(lg - bm);
    float s = e;
    for (int off = 32; off > 0; off >>= 1) s += __shfl_down(s, off, 64);
    if (lane == 0) wsm[w] = s;
    __syncthreads();
    if (t == 0) bs = wsm[0] + wsm[1] + wsm[2] + wsm[3];
    __syncthreads();
    float v = e / bs;
    unsigned short hh, ll; split2(v, hh, ll);
    long long o = ((long long)b * DD + d) * DD + t;
    affHi[o] = hh; affLo[o] = ll;
}

// ---------------------------------------------------------------------------
extern "C" void kernel_launch(void* const* d_in, const int* in_sizes, int n_in,
                              void* d_out, int out_size, void* d_ws, size_t ws_size,
                              hipStream_t stream) {
    const float* v2l   = (const float*)d_in[0];
    const float* l2v   = (const float*)d_in[1];
    const float* w_v2l = (const float*)d_in[2];
    const float* g_v2l = (const float*)d_in[3];
    const float* b_v2l = (const float*)d_in[4];
    const float* w_l2v = (const float*)d_in[5];
    const float* g_l2v = (const float*)d_in[6];
    const float* b_l2v = (const float*)d_in[7];
    float* out = (float*)d_out;

    char* W = (char*)d_ws;
    float* Yv     = (float*)(W + 0);            // 32MB fp32 -> in-place permuted planes
    float* Yl     = (float*)(W + 33554432);     // 32MB
    u16*   YltHi  = (u16*)(W + 67108864);       // 16MB
    u16*   YltLo  = (u16*)(W + 83886080);       // 16MB
    u16*   latHi  = (u16*)(W + 100663296);      //  8MB
    u16*   latLo  = (u16*)(W + 109051904);      //  8MB
    u16*   latTHi = (u16*)(W + 117440512);      //  8MB
    u16*   latTLo = (u16*)(W + 125829120);      //  8MB
    u16*   l2tHi  = (u16*)(W + 134217728);      //  8MB
    u16*   l2tLo  = (u16*)(W + 142606336);      //  8MB
    float* gram   = (float*)(W + 150994944);    //  4MB
    float* rs     = (float*)(W + 155189248);
    u16*   affHi  = (u16*)(W + 155336704);      //  2MB
    u16*   affLo  = (u16*)(W + 157433856);      //  2MB
    u16*   WvHi   = (u16*)(W + 159531008);      //  512KB each
    u16*   WvLo   = WvHi + 262144;
    u16*   WlHi   = WvLo + 262144;
    u16*   WlLo   = WlHi + 262144;

    // K-split latent parts (2 x [B][D][HW] fp32 = 32MB) live in d_out scratch
    float* latPart = (float*)d_out;

    const long long sY   = (long long)DD * CC;     // 524288
    const long long sL   = (long long)DD * HWW;    // 262144
    const long long sG   = (long long)DD * DD;     // 65536
    const long long sX   = (long long)CC * HWW;    // 2097152
    const long long sYp  = (long long)DD * 4096;   // in-place plane stride (u16)

    // weights -> planes
    split_k<<<128, 256, 0, stream>>>(w_v2l, WvHi, WvLo, 32768);
    split_k<<<128, 256, 0, stream>>>(w_l2v, WlHi, WlLo, 32768);

    // G1+G2 fused: Yv/Yl = relu(sc*(W . X^T)+b)  [D=256 x C=2048], K=1024
    gemm2b<0, 1, 1, 1><<<dim3(CC / 128, DD / 128, 32), 512, 0, stream>>>(
        WvHi, WvLo, WlHi, WlLo, 0, HWW,
        v2l, nullptr, l2v, nullptr, sX, HWW,
        Yv, Yl, sY, 0, CC, HWW,
        g_v2l, b_v2l, g_l2v, b_l2v);

    rownorm_split_perm_k<<<dim3(DD, BB), 256, 0, stream>>>(Yv);
    transnorm_k<<<dim3(CC / 32, BB), 256, 0, stream>>>(Yl, YltHi, YltLo);

    // G3 (K-split x2, parity-aligned): latent parts = Yvn(k') . B'(k')^T
    gemm2b<0, 0, 0, 2><<<dim3(HWW / 128, DD / 128, 32), 512, 0, stream>>>(
        (const u16*)Yv, (const u16*)Yv + 2048, nullptr, nullptr, sYp, 4096,
        v2l, nullptr, nullptr, nullptr, sX, HWW,
        latPart, nullptr, sL, (long long)BB * sL, HWW, 1024,
        nullptr, nullptr, nullptr, nullptr);

    latreduce_k<<<dim3(HWW / 32, DD / 32, BB), 256, 0, stream>>>(
        latPart, latHi, latLo, latTHi, latTLo);

    // gram = latent . latent^T  (plane MFMA, fp32 out)
    mfma_gemm<64, 0><<<dim3(4, 2, BB), 256, 0, stream>>>(
        latHi, latLo, sL, HWW, latHi, latLo, sL, HWW,
        gram, nullptr, sG, DD, HWW);

    latnorm_k<<<dim3(BB * DD / 256), 256, 0, stream>>>(gram, rs);
    softmax_k<<<dim3(DD, BB), 256, 0, stream>>>(gram, rs, affHi, affLo);

    // lat2t = latentT . aff^T  [HW,D] -> planes
    mfma_gemm<128, 2><<<dim3(2, 8, BB), 256, 0, stream>>>(
        latTHi, latTLo, sL, DD, affHi, affLo, sG, DD,
        l2tHi, l2tLo, sL, DD, DD);

    // G6: out = Ylt . l2t^T  [C=2048 x HW=1024], K=256, both operands planes
    gemm2b<1, 0, 0, 1><<<dim3(HWW / 128, CC / 128, BB), 512, 0, stream>>>(
        YltHi, YltLo, nullptr, nullptr, sY, DD,
        l2tHi, l2tLo, nullptr, nullptr, sL, DD,
        out, nullptr, sX, 0, HWW, DD,
        nullptr, nullptr, nullptr, nullptr);
}